// Round 1
// baseline (4180.230 us; speedup 1.0000x reference)
//
#include <hip/hip_runtime.h>
#include <math.h>

#define B_ 2
#define S_ 2048
#define D_ 768
#define H_ 12
#define HD_ 64
#define KKEEP 614            // max(1, int(0.3*2048)) = 614
#define M_ (B_*S_)           // 4096

__device__ __forceinline__ unsigned int orderable(float f) {
    unsigned int b = __float_as_uint(f);
    return (b & 0x80000000u) ? ~b : (b | 0x80000000u);
}

// out = A[M,K] @ W[N,K]^T + bias[N]
// LAYOUT 0: out[m*N + n]                       (row-major [M,N])
// LAYOUT 1: out[((b*H+h)*S + s)*HD + d]        (BHSD for attention)
template<int LAYOUT>
__global__ __launch_bounds__(256)
void gemm_nt(const float* __restrict__ A, const float* __restrict__ W,
             const float* __restrict__ bias, float* __restrict__ out,
             int M, int N, int K) {
    __shared__ float As[64][17];
    __shared__ float Ws[64][17];
    const int bm = blockIdx.x * 64;
    const int bn = blockIdx.y * 64;
    const int tid = threadIdx.x;
    const int tx = tid & 15, ty = tid >> 4;
    const int lr = tid >> 2;          // 0..63
    const int lc = (tid & 3) * 4;     // 0,4,8,12
    float acc[4][4] = {};
    for (int kt = 0; kt < K; kt += 16) {
        float4 av = *(const float4*)(A + (size_t)(bm + lr) * K + kt + lc);
        float4 wv = *(const float4*)(W + (size_t)(bn + lr) * K + kt + lc);
        As[lr][lc+0] = av.x; As[lr][lc+1] = av.y; As[lr][lc+2] = av.z; As[lr][lc+3] = av.w;
        Ws[lr][lc+0] = wv.x; Ws[lr][lc+1] = wv.y; Ws[lr][lc+2] = wv.z; Ws[lr][lc+3] = wv.w;
        __syncthreads();
#pragma unroll
        for (int kk = 0; kk < 16; ++kk) {
            float a[4], b[4];
#pragma unroll
            for (int i = 0; i < 4; ++i) a[i] = As[ty*4+i][kk];
#pragma unroll
            for (int j = 0; j < 4; ++j) b[j] = Ws[tx*4+j][kk];
#pragma unroll
            for (int i = 0; i < 4; ++i)
#pragma unroll
                for (int j = 0; j < 4; ++j)
                    acc[i][j] += a[i] * b[j];
        }
        __syncthreads();
    }
#pragma unroll
    for (int i = 0; i < 4; ++i) {
        int m = bm + ty*4 + i;
#pragma unroll
        for (int j = 0; j < 4; ++j) {
            int n = bn + tx*4 + j;
            float v = acc[i][j] + bias[n];
            if (LAYOUT == 0) {
                out[(size_t)m * N + n] = v;
            } else {
                int b_ = m / S_, s_ = m % S_, h_ = n / HD_, d_ = n % HD_;
                out[(((size_t)(b_*H_ + h_))*S_ + s_)*HD_ + d_] = v;
            }
        }
    }
}

// One block (256 threads) per (b, h, q).  Q/K/V in [B,H,S,HD]; O in [B,S,D].
__global__ __launch_bounds__(256)
void attn_kernel(const float* __restrict__ Q, const float* __restrict__ K,
                 const float* __restrict__ V, float* __restrict__ O) {
    const int blk = blockIdx.x;
    const int bh = blk / S_;
    const int q  = blk % S_;
    const int b  = bh / H_;
    const int h  = bh % H_;
    const int tid = threadIdx.x;

    __shared__ float qv[HD_];
    __shared__ float ktile[128][65];   // padded: bank-conflict-free column reads
    __shared__ float sc[S_];           // scores, then softmax weights
    __shared__ float part[2][128];
    __shared__ int   hist[256];
    __shared__ int   suf[256];
    __shared__ float red[256];
    __shared__ float pv[4][64];
    __shared__ unsigned int s_prefix;
    __shared__ int s_kk;

    const float* qp = Q + ((size_t)bh * S_ + q) * HD_;
    if (tid < HD_) qv[tid] = qp[tid];
    if (tid == 0) { s_prefix = 0u; s_kk = KKEEP; }
    __syncthreads();

    const float* Kb = K + (size_t)bh * S_ * HD_;
    const float* Vb = V + (size_t)bh * S_ * HD_;

    // ---- scores: tile K by 128 rows through LDS ----
    for (int t0 = 0; t0 < S_; t0 += 128) {
#pragma unroll
        for (int i = 0; i < 8; ++i) {
            int f  = tid * 8 + i;          // float4 index, 0..2047
            int jl = f >> 4;               // local key row
            int d0 = (f & 15) * 4;
            float4 kv = *(const float4*)(Kb + ((size_t)(t0 + jl)) * HD_ + d0);
            ktile[jl][d0+0] = kv.x; ktile[jl][d0+1] = kv.y;
            ktile[jl][d0+2] = kv.z; ktile[jl][d0+3] = kv.w;
        }
        __syncthreads();
        int jl = tid & 127, half = tid >> 7;
        int dbase = half * 32;
        float p = 0.f;
#pragma unroll
        for (int dd = 0; dd < 32; ++dd) p += qv[dbase + dd] * ktile[jl][dbase + dd];
        part[half][jl] = p;
        __syncthreads();
        if (tid < 128) sc[t0 + tid] = (part[0][tid] + part[1][tid]) * 0.125f;
        __syncthreads();
    }

    // ---- row max (global max is always kept by top-k) ----
    float mloc = -1e30f;
    for (int j = tid; j < S_; j += 256) mloc = fmaxf(mloc, sc[j]);
    red[tid] = mloc;
    __syncthreads();
    for (int off = 128; off > 0; off >>= 1) {
        if (tid < off) red[tid] = fmaxf(red[tid], red[tid+off]);
        __syncthreads();
    }
    const float m = red[0];
    __syncthreads();

    // ---- exact 614th-largest threshold: 4-pass radix select on float bits ----
    for (int pass = 3; pass >= 0; --pass) {
        hist[tid] = 0;
        __syncthreads();
        unsigned int pref  = s_prefix;
        unsigned int hmask = (pass == 3) ? 0u : (0xFFFFFFFFu << ((pass+1)*8));
        for (int j = tid; j < S_; j += 256) {
            unsigned int u = orderable(sc[j]);
            if ((u & hmask) == pref)
                atomicAdd(&hist[(u >> (pass*8)) & 255], 1);
        }
        __syncthreads();
        // inclusive suffix-sum (Hillis-Steele), 8 steps
        suf[tid] = hist[tid];
        __syncthreads();
        for (int off = 1; off < 256; off <<= 1) {
            int add = (tid + off < 256) ? suf[tid + off] : 0;
            __syncthreads();
            suf[tid] += add;
            __syncthreads();
        }
        int kkc   = s_kk;
        int sme   = suf[tid];
        int snext = (tid < 255) ? suf[tid + 1] : 0;
        __syncthreads();
        if (sme >= kkc && snext < kkc) {   // exactly one thread
            s_prefix = pref | ((unsigned int)tid << (pass*8));
            s_kk     = kkc - snext;
        }
        __syncthreads();
    }
    const unsigned int T = s_prefix;

    // ---- masked softmax weights (un-normalized) + denominator ----
    float lloc = 0.f;
    for (int j = tid; j < S_; j += 256) {
        float s = sc[j];
        float w = (orderable(s) >= T) ? expf(s - m) : 0.f;
        sc[j] = w;
        lloc += w;
    }
    red[tid] = lloc;
    __syncthreads();
    for (int off = 128; off > 0; off >>= 1) {
        if (tid < off) red[tid] += red[tid + off];
        __syncthreads();
    }
    const float linv = 1.f / red[0];
    __syncthreads();

    // ---- PV: wave-uniform j, lanes over d (coalesced V, broadcast w) ----
    const int d  = tid & 63;
    const int jp = tid >> 6;
    float acc = 0.f;
    for (int j = jp * 512; j < jp * 512 + 512; ++j)
        acc += sc[j] * Vb[(size_t)j * HD_ + d];
    pv[jp][d] = acc;
    __syncthreads();
    if (tid < 64) {
        float o = (pv[0][tid] + pv[1][tid] + pv[2][tid] + pv[3][tid]) * linv;
        O[((size_t)b * S_ + q) * D_ + h * HD_ + tid] = o;
    }
}

extern "C" void kernel_launch(void* const* d_in, const int* in_sizes, int n_in,
                              void* d_out, int out_size, void* d_ws, size_t ws_size,
                              hipStream_t stream) {
    const float* x  = (const float*)d_in[0];
    const float* Wq = (const float*)d_in[1];
    const float* bq = (const float*)d_in[2];
    const float* Wk = (const float*)d_in[3];
    const float* bk = (const float*)d_in[4];
    const float* Wv = (const float*)d_in[5];
    const float* bv = (const float*)d_in[6];
    const float* Wo = (const float*)d_in[7];
    const float* bo = (const float*)d_in[8];
    float* out = (float*)d_out;

    const size_t plane = (size_t)M_ * D_;   // 3.1M floats
    float* Qw = (float*)d_ws;
    float* Kw = Qw + plane;
    float* Vw = Kw + plane;
    float* AO = Vw + plane;

    dim3 g(M_/64, D_/64);                   // (64, 12)
    gemm_nt<1><<<g, 256, 0, stream>>>(x, Wq, bq, Qw, M_, D_, D_);
    gemm_nt<1><<<g, 256, 0, stream>>>(x, Wk, bk, Kw, M_, D_, D_);
    gemm_nt<1><<<g, 256, 0, stream>>>(x, Wv, bv, Vw, M_, D_, D_);

    attn_kernel<<<B_*H_*S_, 256, 0, stream>>>(Qw, Kw, Vw, AO);

    gemm_nt<0><<<g, 256, 0, stream>>>(AO, Wo, bo, out, M_, D_, D_);
}

// Round 2
// 1187.559 us; speedup vs baseline: 3.5200x; 3.5200x over previous
//
#include <hip/hip_runtime.h>
#include <math.h>

#define B_ 2
#define S_ 2048
#define D_ 768
#define H_ 12
#define HD_ 64
#define KKEEP 614            // max(1, int(0.3*2048)) = 614
#define M_ (B_*S_)           // 4096
#define TQ 8                 // query rows per attention block

__device__ __forceinline__ unsigned int orderable(float f) {
    unsigned int b = __float_as_uint(f);
    return (b & 0x80000000u) ? ~b : (b | 0x80000000u);
}

// out = A[M,K] @ W[N,K]^T + bias[N]
// LAYOUT 0: out[m*N + n]                          (row-major [M,N])
// LAYOUT 1: out[((b*H+h)*S + s)*HD + d]           (BHSD: Q, V)
// LAYOUT 2: out[((b*H+h)*HD + d)*S + s]           (BHDS: K transposed)
template<int LAYOUT>
__global__ __launch_bounds__(256)
void gemm_nt(const float* __restrict__ A, const float* __restrict__ W,
             const float* __restrict__ bias, float* __restrict__ out,
             int M, int N, int K) {
    __shared__ float As[64][17];
    __shared__ float Ws[64][17];
    const int bm = blockIdx.x * 64;
    const int bn = blockIdx.y * 64;
    const int tid = threadIdx.x;
    const int tx = tid & 15, ty = tid >> 4;
    const int lr = tid >> 2;          // 0..63
    const int lc = (tid & 3) * 4;     // 0,4,8,12
    float acc[4][4] = {};
    for (int kt = 0; kt < K; kt += 16) {
        float4 av = *(const float4*)(A + (size_t)(bm + lr) * K + kt + lc);
        float4 wv = *(const float4*)(W + (size_t)(bn + lr) * K + kt + lc);
        As[lr][lc+0] = av.x; As[lr][lc+1] = av.y; As[lr][lc+2] = av.z; As[lr][lc+3] = av.w;
        Ws[lr][lc+0] = wv.x; Ws[lr][lc+1] = wv.y; Ws[lr][lc+2] = wv.z; Ws[lr][lc+3] = wv.w;
        __syncthreads();
#pragma unroll
        for (int kk = 0; kk < 16; ++kk) {
            float a[4], b[4];
#pragma unroll
            for (int i = 0; i < 4; ++i) a[i] = As[ty*4+i][kk];
#pragma unroll
            for (int j = 0; j < 4; ++j) b[j] = Ws[tx*4+j][kk];
#pragma unroll
            for (int i = 0; i < 4; ++i)
#pragma unroll
                for (int j = 0; j < 4; ++j)
                    acc[i][j] += a[i] * b[j];
        }
        __syncthreads();
    }
#pragma unroll
    for (int i = 0; i < 4; ++i) {
        int m = bm + ty*4 + i;
#pragma unroll
        for (int j = 0; j < 4; ++j) {
            int n = bn + tx*4 + j;
            float v = acc[i][j] + bias[n];
            if (LAYOUT == 0) {
                out[(size_t)m * N + n] = v;
            } else if (LAYOUT == 1) {
                int b_ = m / S_, s_ = m % S_, h_ = n / HD_, d_ = n % HD_;
                out[(((size_t)(b_*H_ + h_))*S_ + s_)*HD_ + d_] = v;
            } else {
                int b_ = m / S_, s_ = m % S_, h_ = n / HD_, d_ = n % HD_;
                out[(((size_t)(b_*H_ + h_))*HD_ + d_)*S_ + s_] = v;
            }
        }
    }
}

// One block (256 thr) = TQ=8 query rows of one (b,h).
// Kt is [B,H,HD,S]; Q,V are [B,H,S,HD]; O is [B,S,D].
__global__ __launch_bounds__(256)
void attn_kernel(const float* __restrict__ Q, const float* __restrict__ Kt,
                 const float* __restrict__ V, float* __restrict__ O) {
    // XCD swizzle: blockIdx%8 ~ XCD; give each XCD 3 (b,h) pairs -> 3MB < 4MB L2
    const int bid  = blockIdx.x;           // 0..6143
    const int xcd  = bid & 7;
    const int sub  = (bid >> 3) % 3;
    const int tile = bid / 24;             // 0..255
    const int bh   = xcd * 3 + sub;        // 0..23
    const int b    = bh / H_;
    const int h    = bh % H_;
    const int q0   = tile * TQ;
    const int tid  = threadIdx.x;
    const int lane = tid & 63;
    const int wave = tid >> 6;

    __shared__ float scT[S_][TQ];          // 64KB: final softmax weights, [j][q]
    __shared__ float qv[TQ][HD_];          // 2KB (pre-scaled by 1/8)
    __shared__ int   hist[TQ][256];        // 8KB (aliased as pv later)
    __shared__ float partial[4][TQ];
    __shared__ float mrow[TQ];
    __shared__ float linv[TQ];
    __shared__ unsigned int prefix[TQ];
    __shared__ int kkarr[TQ];

    // ---- init: load q (pre-scaled), zero hist, init select state ----
    if (tid < 128) {
        int r = tid >> 4, d0 = (tid & 15) * 4;
        const float* qp = Q + (((size_t)bh * S_) + q0 + r) * HD_ + d0;
        float4 v4 = *(const float4*)qp;
        qv[r][d0+0] = v4.x * 0.125f; qv[r][d0+1] = v4.y * 0.125f;
        qv[r][d0+2] = v4.z * 0.125f; qv[r][d0+3] = v4.w * 0.125f;
    }
    for (int z = tid; z < TQ*256; z += 256) ((int*)hist)[z] = 0;
    if (tid < TQ) { prefix[tid] = 0u; kkarr[tid] = KKEEP; }
    __syncthreads();                                        // [A]

    // ---- scores: acc[q][i] = s[q][tid + 256*i], all in registers ----
    const float* Ktb = Kt + (size_t)bh * HD_ * S_;
    float acc[TQ][8];
#pragma unroll
    for (int q = 0; q < TQ; ++q)
#pragma unroll
        for (int i = 0; i < 8; ++i) acc[q][i] = 0.f;

    for (int d = 0; d < HD_; ++d) {
        float qq[TQ];
#pragma unroll
        for (int q = 0; q < TQ; ++q) qq[q] = qv[q][d];
        const float* kp = Ktb + (size_t)d * S_ + tid;
        float kv[8];
#pragma unroll
        for (int i = 0; i < 8; ++i) kv[i] = kp[256*i];
#pragma unroll
        for (int q = 0; q < TQ; ++q)
#pragma unroll
            for (int i = 0; i < 8; ++i) acc[q][i] += qq[q] * kv[i];
    }

    // ---- per-row max: thread-local -> wave shuffle -> LDS partial ----
    {
        float mq[TQ];
#pragma unroll
        for (int q = 0; q < TQ; ++q) {
            float m = acc[q][0];
#pragma unroll
            for (int i = 1; i < 8; ++i) m = fmaxf(m, acc[q][i]);
            mq[q] = m;
        }
#pragma unroll
        for (int off = 32; off > 0; off >>= 1)
#pragma unroll
            for (int q = 0; q < TQ; ++q)
                mq[q] = fmaxf(mq[q], __shfl_down(mq[q], off, 64));
        if (lane == 0)
#pragma unroll
            for (int q = 0; q < TQ; ++q) partial[wave][q] = mq[q];
    }

    // ---- selection pass 3 build (no barrier needed: hist/prefix pre-inited) ----
    // (histogram over top byte of orderable score)
#pragma unroll
    for (int q = 0; q < TQ; ++q)
#pragma unroll
        for (int i = 0; i < 8; ++i) {
            unsigned u = orderable(acc[q][i]);
            atomicAdd(&hist[q][(u >> 24) & 255], 1);
        }
    __syncthreads();                                        // [B]
    if (tid < TQ) {   // combine row max (partials ready)
        float m = partial[0][tid];
        m = fmaxf(m, partial[1][tid]);
        m = fmaxf(m, partial[2][tid]);
        m = fmaxf(m, partial[3][tid]);
        mrow[tid] = m;
    }

    // ---- 4-pass radix select: scan pass p, then build pass p-1 ----
    const unsigned hmasks[4] = {0xFFFFFF00u, 0xFFFF0000u, 0xFF000000u, 0u};
    for (int p = 3; p >= 0; --p) {
        // scan: wave w handles rows 2w, 2w+1; shuffle suffix-scan, zero hist after
        int shift = p * 8;
#pragma unroll
        for (int rr = 0; rr < 2; ++rr) {
            int r = wave * 2 + rr;
            int4 h4 = *(const int4*)&hist[r][lane * 4];
            int s3 = h4.w, s2 = h4.z + s3, s1 = h4.y + s2, s0 = h4.x + s1;
            int x = s0;
#pragma unroll
            for (int off = 1; off < 64; off <<= 1) {
                int v = __shfl_down(x, off, 64);
                if (lane + off < 64) x += v;
            }
            int A = x - s0;                 // suffix over lanes > lane
            int kk = kkarr[r];
            int suf[4] = { s0 + A, s1 + A, s2 + A, s3 + A };
            int nxt[4] = { s1 + A, s2 + A, s3 + A, A };
#pragma unroll
            for (int i = 0; i < 4; ++i) {
                if (suf[i] >= kk && nxt[i] < kk) {      // exactly one (lane,i)
                    prefix[r] = prefix[r] | ((unsigned)(lane * 4 + i) << shift);
                    kkarr[r] = kk - nxt[i];
                }
            }
            *(int4*)&hist[r][lane * 4] = make_int4(0, 0, 0, 0);
        }
        __syncthreads();                                    // scan done, hist zeroed

        if (p == 0) break;
        // build pass p-1 from registers
        unsigned pref[TQ];
#pragma unroll
        for (int q = 0; q < TQ; ++q) pref[q] = prefix[q];
        unsigned hm = hmasks[p - 1];
        int sh = (p - 1) * 8;
#pragma unroll
        for (int q = 0; q < TQ; ++q)
#pragma unroll
            for (int i = 0; i < 8; ++i) {
                unsigned u = orderable(acc[q][i]);
                if (((u ^ pref[q]) & hm) == 0)
                    atomicAdd(&hist[q][(u >> sh) & 255], 1);
            }
        __syncthreads();                                    // build done
    }

    // ---- weights + row-sum (threshold T[q] = prefix[q] = exact 614th largest) ----
    {
        unsigned Tq[TQ]; float mq[TQ], ls[TQ];
#pragma unroll
        for (int q = 0; q < TQ; ++q) { Tq[q] = prefix[q]; mq[q] = mrow[q]; ls[q] = 0.f; }
#pragma unroll
        for (int q = 0; q < TQ; ++q)
#pragma unroll
            for (int i = 0; i < 8; ++i) {
                unsigned u = orderable(acc[q][i]);
                float w = (u >= Tq[q]) ? __expf(acc[q][i] - mq[q]) : 0.f;
                acc[q][i] = w;
                ls[q] += w;
            }
        // write weights to scT[j][q] (2 x float4 per i)
#pragma unroll
        for (int i = 0; i < 8; ++i) {
            int j = tid + 256 * i;
            float4 lo = make_float4(acc[0][i], acc[1][i], acc[2][i], acc[3][i]);
            float4 hi = make_float4(acc[4][i], acc[5][i], acc[6][i], acc[7][i]);
            *(float4*)&scT[j][0] = lo;
            *(float4*)&scT[j][4] = hi;
        }
#pragma unroll
        for (int off = 32; off > 0; off >>= 1)
#pragma unroll
            for (int q = 0; q < TQ; ++q)
                ls[q] += __shfl_down(ls[q], off, 64);
        if (lane == 0)
#pragma unroll
            for (int q = 0; q < TQ; ++q) partial[wave][q] = ls[q];
    }
    __syncthreads();                                        // [D]
    if (tid < TQ)
        linv[tid] = 1.f / (partial[0][tid] + partial[1][tid] +
                           partial[2][tid] + partial[3][tid]);

    // ---- PV: wave c sums j-chunk [c*512, c*512+512); lanes over d ----
    float* pv = (float*)hist;              // alias: 4*8*64*4B = 8KB
    {
        const float* Vb = V + (size_t)bh * S_ * HD_;
        const int d = lane, c = wave;
        float o[TQ];
#pragma unroll
        for (int q = 0; q < TQ; ++q) o[q] = 0.f;
#pragma unroll 4
        for (int jj = 0; jj < 512; ++jj) {
            int j = c * 512 + jj;
            float4 w0 = *(const float4*)&scT[j][0];   // broadcast (uniform addr)
            float4 w1 = *(const float4*)&scT[j][4];
            float vv = Vb[(size_t)j * HD_ + d];       // coalesced
            o[0] += w0.x * vv; o[1] += w0.y * vv; o[2] += w0.z * vv; o[3] += w0.w * vv;
            o[4] += w1.x * vv; o[5] += w1.y * vv; o[6] += w1.z * vv; o[7] += w1.w * vv;
        }
#pragma unroll
        for (int q = 0; q < TQ; ++q) pv[(c * TQ + q) * HD_ + d] = o[q];
    }
    __syncthreads();                                        // [E]
#pragma unroll
    for (int oidx = 0; oidx < 2; ++oidx) {
        int o = tid + oidx * 256;          // 0..511 -> (q,d)
        int q = o >> 6, d = o & 63;
        float s = pv[(0 * TQ + q) * HD_ + d] + pv[(1 * TQ + q) * HD_ + d] +
                  pv[(2 * TQ + q) * HD_ + d] + pv[(3 * TQ + q) * HD_ + d];
        O[((size_t)b * S_ + q0 + q) * D_ + h * HD_ + d] = s * linv[q];
    }
}

extern "C" void kernel_launch(void* const* d_in, const int* in_sizes, int n_in,
                              void* d_out, int out_size, void* d_ws, size_t ws_size,
                              hipStream_t stream) {
    const float* x  = (const float*)d_in[0];
    const float* Wq = (const float*)d_in[1];
    const float* bq = (const float*)d_in[2];
    const float* Wk = (const float*)d_in[3];
    const float* bk = (const float*)d_in[4];
    const float* Wv = (const float*)d_in[5];
    const float* bv = (const float*)d_in[6];
    const float* Wo = (const float*)d_in[7];
    const float* bo = (const float*)d_in[8];
    float* out = (float*)d_out;

    const size_t plane = (size_t)M_ * D_;   // 3.1M floats
    float* Qw = (float*)d_ws;
    float* Kw = Qw + plane;                 // transposed [B,H,HD,S]
    float* Vw = Kw + plane;
    float* AO = Vw + plane;

    dim3 g(M_/64, D_/64);                   // (64, 12)
    gemm_nt<1><<<g, 256, 0, stream>>>(x, Wq, bq, Qw, M_, D_, D_);
    gemm_nt<2><<<g, 256, 0, stream>>>(x, Wk, bk, Kw, M_, D_, D_);
    gemm_nt<1><<<g, 256, 0, stream>>>(x, Wv, bv, Vw, M_, D_, D_);

    attn_kernel<<<(M_/TQ)*H_, 256, 0, stream>>>(Qw, Kw, Vw, AO);

    gemm_nt<0><<<g, 256, 0, stream>>>(AO, Wo, bo, out, M_, D_, D_);
}

// Round 3
// 798.622 us; speedup vs baseline: 5.2343x; 1.4870x over previous
//
#include <hip/hip_runtime.h>
#include <math.h>

#define B_ 2
#define S_ 2048
#define D_ 768
#define H_ 12
#define HD_ 64
#define KKEEP 614            // max(1, int(0.3*2048))
#define M_ (B_*S_)           // 4096
#define KD_ 768

typedef __attribute__((ext_vector_type(8))) short bf8;   // 8 bf16 = 4 VGPR (MFMA A/B frag)
typedef __attribute__((ext_vector_type(4))) float f4;    // MFMA 16x16 C/D frag

__device__ __forceinline__ unsigned short f2bf(float f) {   // RNE fp32->bf16
    unsigned u = __float_as_uint(f);
    u += 0x7FFF + ((u >> 16) & 1);
    return (unsigned short)(u >> 16);
}
__device__ __forceinline__ float bf2f(unsigned short h) {
    return __uint_as_float((unsigned)h << 16);
}
__device__ __forceinline__ unsigned orderable(float f) {
    unsigned b = __float_as_uint(f);
    return (b & 0x80000000u) ? ~b : (b | 0x80000000u);
}

// fp32 -> (bf16 hi, bf16 lo) planes; a = hi + lo to ~16 mantissa bits
__global__ void split_kernel(const float* __restrict__ src,
                             unsigned short* __restrict__ hi,
                             unsigned short* __restrict__ lo, int n) {
    int i = blockIdx.x * blockDim.x + threadIdx.x;
    int stride = gridDim.x * blockDim.x;
    for (; i < n; i += stride) {
        float f = src[i];
        unsigned short h = f2bf(f);
        hi[i] = h;
        lo[i] = f2bf(f - bf2f(h));
    }
}

// C[m][n] = sum_k A[m][k]*W[n][k] + bias[n], split-bf16 (3 MFMA per product).
// Tile 128(M) x 64(N), BK=32, 256 thr = 4 waves, wave owns 32-row strip.
// MODE 0: fp32 out[m*768+n]
// MODE 1: bf16 hi/lo planes, BHSD  [b][h][s][d]   (Q, K)
// MODE 2: bf16 hi/lo planes, BHDS  [b][h][d][s]   (V transposed)
template<int MODE>
__global__ __launch_bounds__(256)
void gemm_bf16s(const unsigned short* __restrict__ Ahi, const unsigned short* __restrict__ Alo,
                const unsigned short* __restrict__ Whi, const unsigned short* __restrict__ Wlo,
                const float* __restrict__ bias,
                float* __restrict__ outf,
                unsigned short* __restrict__ ohi, unsigned short* __restrict__ olo) {
    __shared__ unsigned short Ah[128][32], Al[128][32], Bh[64][32], Bl[64][32];  // 24KB
    const int bm = blockIdx.x * 128, bn = blockIdx.y * 64;
    const int tid = threadIdx.x, lane = tid & 63, wave = tid >> 6;
    const int col = lane & 15, quad = lane >> 4;

    f4 acc[2][4];
#pragma unroll
    for (int mi = 0; mi < 2; ++mi)
#pragma unroll
        for (int ni = 0; ni < 4; ++ni) { f4 z = {0.f,0.f,0.f,0.f}; acc[mi][ni] = z; }

    for (int kt = 0; kt < KD_; kt += 32) {
        __syncthreads();
        // stage A (128x32 x2 planes): 512 x 16B per plane, 2 per thread
#pragma unroll
        for (int c = 0; c < 2; ++c) {
            int idx = c * 256 + tid;
            int row = idx >> 2, ko = (idx & 3) * 8;
            *(uint4*)&Ah[row][ko] = *(const uint4*)&Ahi[(size_t)(bm + row) * KD_ + kt + ko];
            *(uint4*)&Al[row][ko] = *(const uint4*)&Alo[(size_t)(bm + row) * KD_ + kt + ko];
        }
        {   // stage W (64x32 x2 planes): 256 x 16B per plane, 1 per thread
            int row = tid >> 2, ko = (tid & 3) * 8;
            *(uint4*)&Bh[row][ko] = *(const uint4*)&Whi[(size_t)(bn + row) * KD_ + kt + ko];
            *(uint4*)&Bl[row][ko] = *(const uint4*)&Wlo[(size_t)(bn + row) * KD_ + kt + ko];
        }
        __syncthreads();

        bf8 af[2][2], wf[4][2];
#pragma unroll
        for (int mi = 0; mi < 2; ++mi) {
            int r = wave * 32 + mi * 16 + col;
            af[mi][0] = *(const bf8*)&Ah[r][quad * 8];
            af[mi][1] = *(const bf8*)&Al[r][quad * 8];
        }
#pragma unroll
        for (int ni = 0; ni < 4; ++ni) {
            int r = ni * 16 + col;
            wf[ni][0] = *(const bf8*)&Bh[r][quad * 8];
            wf[ni][1] = *(const bf8*)&Bl[r][quad * 8];
        }
#pragma unroll
        for (int mi = 0; mi < 2; ++mi)
#pragma unroll
            for (int ni = 0; ni < 4; ++ni) {
                acc[mi][ni] = __builtin_amdgcn_mfma_f32_16x16x32_bf16(af[mi][0], wf[ni][0], acc[mi][ni], 0, 0, 0);
                acc[mi][ni] = __builtin_amdgcn_mfma_f32_16x16x32_bf16(af[mi][1], wf[ni][0], acc[mi][ni], 0, 0, 0);
                acc[mi][ni] = __builtin_amdgcn_mfma_f32_16x16x32_bf16(af[mi][0], wf[ni][1], acc[mi][ni], 0, 0, 0);
            }
    }

    float bv[4];
#pragma unroll
    for (int ni = 0; ni < 4; ++ni) bv[ni] = bias[bn + ni * 16 + col];
#pragma unroll
    for (int mi = 0; mi < 2; ++mi)
#pragma unroll
        for (int ni = 0; ni < 4; ++ni)
#pragma unroll
            for (int r = 0; r < 4; ++r) {
                int m = bm + wave * 32 + mi * 16 + quad * 4 + r;  // C row = quad*4+reg
                int n = bn + ni * 16 + col;                       // C col = lane&15
                float v = acc[mi][ni][r] + bv[ni];
                if (MODE == 0) {
                    outf[(size_t)m * D_ + n] = v;
                } else {
                    int b = m >> 11, s = m & 2047, h = n >> 6, d = n & 63;
                    size_t idx = (MODE == 1)
                        ? ((((size_t)b * H_ + h) * S_ + s) * HD_ + d)
                        : ((((size_t)b * H_ + h) * HD_ + d) * S_ + s);
                    unsigned short hh = f2bf(v);
                    ohi[idx] = hh;
                    olo[idx] = f2bf(v - bf2f(hh));
                }
            }
}

// Attention: block = 16 q rows of one (b,h); 512 thr = 8 waves; wave owns 256 keys.
// Scores via MFMA into C-layout regs (64 fp32/lane), exact radix top-k, softmax,
// PV via MFMA (P bounced through LDS to A-layout; V^T frags direct from global).
__global__ __launch_bounds__(512)
void attn_kernel(const unsigned short* __restrict__ Qhi, const unsigned short* __restrict__ Qlo,
                 const unsigned short* __restrict__ Khi, const unsigned short* __restrict__ Klo,
                 const unsigned short* __restrict__ Vthi, const unsigned short* __restrict__ Vtlo,
                 unsigned short* __restrict__ AOhi, unsigned short* __restrict__ AOlo) {
    const int bid = blockIdx.x;            // 3072 = 24 bh * 128 q-tiles
    const int xcd = bid & 7, sub = (bid >> 3) % 3, tile = bid / 24;
    const int bh = xcd * 3 + sub;          // L2 locality: 3 (b,h) per XCD
    const int b = bh / H_, h = bh % H_;
    const int q0 = tile * 16;
    const int tid = threadIdx.x, lane = tid & 63, wave = tid >> 6;
    const int col = lane & 15, quad = lane >> 4;

    __shared__ float osum[8][16][64];                 // 32KB; first 16KB doubles as hist
    int (*hist)[256] = (int(*)[256])osum;
    __shared__ unsigned short Pscr[8][2][16][32];     // 16KB: per-wave P hi/lo bounce
    __shared__ float partial[8][16];
    __shared__ float mrow[16], linv[16];
    __shared__ unsigned prefix[16];
    __shared__ int kkarr[16];

    for (int z = tid; z < 16 * 256; z += 512) ((int*)hist)[z] = 0;
    if (tid < 16) { prefix[tid] = 0u; kkarr[tid] = KKEEP; }

    // Q A-frags direct from global: m = lane&15 = q-local, k = quad*8+j
    const size_t qbase = ((size_t)bh * S_ + q0 + col) * HD_;
    bf8 qh[2], ql[2];
    qh[0] = *(const bf8*)&Qhi[qbase + quad * 8];
    qh[1] = *(const bf8*)&Qhi[qbase + 32 + quad * 8];
    ql[0] = *(const bf8*)&Qlo[qbase + quad * 8];
    ql[1] = *(const bf8*)&Qlo[qbase + 32 + quad * 8];
    __syncthreads();   // hist zero visible

    // ---- QK^T: sc[t][r] : q = quad*4+r, k = wave*256 + t*16 + col ----
    float sc[16][4];
    const size_t kbb = (size_t)bh * S_ * HD_;
    for (int t = 0; t < 16; ++t) {
        const size_t kr = kbb + (size_t)(wave * 256 + t * 16 + col) * HD_;
        bf8 kh0 = *(const bf8*)&Khi[kr + quad * 8];
        bf8 kh1 = *(const bf8*)&Khi[kr + 32 + quad * 8];
        bf8 kl0 = *(const bf8*)&Klo[kr + quad * 8];
        bf8 kl1 = *(const bf8*)&Klo[kr + 32 + quad * 8];
        f4 a = {0.f, 0.f, 0.f, 0.f};
        a = __builtin_amdgcn_mfma_f32_16x16x32_bf16(qh[0], kh0, a, 0, 0, 0);
        a = __builtin_amdgcn_mfma_f32_16x16x32_bf16(qh[1], kh1, a, 0, 0, 0);
        a = __builtin_amdgcn_mfma_f32_16x16x32_bf16(ql[0], kh0, a, 0, 0, 0);
        a = __builtin_amdgcn_mfma_f32_16x16x32_bf16(ql[1], kh1, a, 0, 0, 0);
        a = __builtin_amdgcn_mfma_f32_16x16x32_bf16(qh[0], kl0, a, 0, 0, 0);
        a = __builtin_amdgcn_mfma_f32_16x16x32_bf16(qh[1], kl1, a, 0, 0, 0);
        sc[t][0] = a[0] * 0.125f; sc[t][1] = a[1] * 0.125f;
        sc[t][2] = a[2] * 0.125f; sc[t][3] = a[3] * 0.125f;
    }

    // ---- row max (shuffle within 16-lane groups; q = quad*4+r) + pass-3 hist ----
    {
        float mq[4] = {-1e30f, -1e30f, -1e30f, -1e30f};
        for (int t = 0; t < 16; ++t)
#pragma unroll
            for (int r = 0; r < 4; ++r) mq[r] = fmaxf(mq[r], sc[t][r]);
#pragma unroll
        for (int off = 8; off >= 1; off >>= 1)
#pragma unroll
            for (int r = 0; r < 4; ++r) mq[r] = fmaxf(mq[r], __shfl_xor(mq[r], off, 64));
        if (col == 0)
#pragma unroll
            for (int r = 0; r < 4; ++r) partial[wave][quad * 4 + r] = mq[r];
    }
    for (int t = 0; t < 16; ++t)
#pragma unroll
        for (int r = 0; r < 4; ++r)
            atomicAdd(&hist[quad * 4 + r][orderable(sc[t][r]) >> 24], 1);
    __syncthreads();
    if (tid < 16) {
        float m = partial[0][tid];
        for (int w = 1; w < 8; ++w) m = fmaxf(m, partial[w][tid]);
        mrow[tid] = m;
    }

    // ---- exact 614th-largest threshold: 4-pass radix select ----
    const unsigned hmasks[4] = {0xFFFFFF00u, 0xFFFF0000u, 0xFF000000u, 0u};
    for (int p = 3; p >= 0; --p) {
        int shift = p * 8;
#pragma unroll
        for (int rr = 0; rr < 2; ++rr) {      // wave scans rows 2w, 2w+1
            int r = wave * 2 + rr;
            int4 h4 = *(const int4*)&hist[r][lane * 4];
            int s3 = h4.w, s2 = h4.z + s3, s1 = h4.y + s2, s0 = h4.x + s1;
            int x = s0;
#pragma unroll
            for (int off = 1; off < 64; off <<= 1) {
                int v = __shfl_down(x, off, 64);
                if (lane + off < 64) x += v;
            }
            int A = x - s0;
            int kk = kkarr[r];
            int suf[4] = { s0 + A, s1 + A, s2 + A, s3 + A };
            int nxt[4] = { s1 + A, s2 + A, s3 + A, A };
#pragma unroll
            for (int i = 0; i < 4; ++i)
                if (suf[i] >= kk && nxt[i] < kk) {       // exactly one (lane,i)
                    prefix[r] |= (unsigned)(lane * 4 + i) << shift;
                    kkarr[r] = kk - nxt[i];
                }
            *(int4*)&hist[r][lane * 4] = make_int4(0, 0, 0, 0);
        }
        __syncthreads();
        if (p == 0) break;
        unsigned pr[4];
#pragma unroll
        for (int r = 0; r < 4; ++r) pr[r] = prefix[quad * 4 + r];
        unsigned hm = hmasks[p - 1];
        int sh = (p - 1) * 8;
        for (int t = 0; t < 16; ++t)
#pragma unroll
            for (int r = 0; r < 4; ++r) {
                unsigned u = orderable(sc[t][r]);
                if (((u ^ pr[r]) & hm) == 0)
                    atomicAdd(&hist[quad * 4 + r][(u >> sh) & 255], 1);
            }
        __syncthreads();
    }

    // ---- masked softmax weights + row sum ----
    {
        unsigned Tu[4]; float mr[4], ls[4];
#pragma unroll
        for (int r = 0; r < 4; ++r) {
            Tu[r] = prefix[quad * 4 + r];
            mr[r] = mrow[quad * 4 + r];
            ls[r] = 0.f;
        }
        for (int t = 0; t < 16; ++t)
#pragma unroll
            for (int r = 0; r < 4; ++r) {
                float s = sc[t][r];
                float w = (orderable(s) >= Tu[r]) ? __expf(s - mr[r]) : 0.f;
                sc[t][r] = w;
                ls[r] += w;
            }
#pragma unroll
        for (int off = 8; off >= 1; off >>= 1)
#pragma unroll
            for (int r = 0; r < 4; ++r) ls[r] += __shfl_xor(ls[r], off, 64);
        if (col == 0)
#pragma unroll
            for (int r = 0; r < 4; ++r) partial[wave][quad * 4 + r] = ls[r];
    }
    __syncthreads();
    if (tid < 16) {
        float l = 0.f;
        for (int w = 0; w < 8; ++w) l += partial[w][tid];
        linv[tid] = 1.f / l;
    }
    __syncthreads();

    // ---- PV: per 32-k chunk, bounce P (hi/lo bf16) C-layout -> A-layout via LDS ----
    f4 od[4];
#pragma unroll
    for (int dt = 0; dt < 4; ++dt) { f4 z = {0.f,0.f,0.f,0.f}; od[dt] = z; }
    const size_t vbb = (size_t)bh * HD_ * S_;
    for (int c = 0; c < 8; ++c) {
#pragma unroll
        for (int tt = 0; tt < 2; ++tt) {
            int t = c * 2 + tt;
#pragma unroll
            for (int r = 0; r < 4; ++r) {
                float w = sc[t][r];
                unsigned short hh = f2bf(w);
                Pscr[wave][0][quad * 4 + r][tt * 16 + col] = hh;
                Pscr[wave][1][quad * 4 + r][tt * 16 + col] = f2bf(w - bf2f(hh));
            }
        }
        // same-wave LDS RAW: compiler inserts lgkmcnt wait
        bf8 ph = *(const bf8*)&Pscr[wave][0][col][quad * 8];
        bf8 pl = *(const bf8*)&Pscr[wave][1][col][quad * 8];
        const size_t sbase = (size_t)(wave * 256 + c * 32 + quad * 8);
#pragma unroll
        for (int dt = 0; dt < 4; ++dt) {
            const size_t vr = vbb + (size_t)(dt * 16 + col) * S_ + sbase;
            bf8 vh = *(const bf8*)&Vthi[vr];
            bf8 vl = *(const bf8*)&Vtlo[vr];
            od[dt] = __builtin_amdgcn_mfma_f32_16x16x32_bf16(ph, vh, od[dt], 0, 0, 0);
            od[dt] = __builtin_amdgcn_mfma_f32_16x16x32_bf16(pl, vh, od[dt], 0, 0, 0);
            od[dt] = __builtin_amdgcn_mfma_f32_16x16x32_bf16(ph, vl, od[dt], 0, 0, 0);
        }
    }
#pragma unroll
    for (int dt = 0; dt < 4; ++dt)
#pragma unroll
        for (int r = 0; r < 4; ++r)
            osum[wave][quad * 4 + r][dt * 16 + col] = od[dt][r];
    __syncthreads();

    // ---- reduce 8 wave-partials, normalize, emit hi/lo planes (row-major [M][768]) ----
    for (int o = tid; o < 1024; o += 512) {
        int q = o >> 6, d = o & 63;
        float s = 0.f;
        for (int w = 0; w < 8; ++w) s += osum[w][q][d];
        s *= linv[q];
        size_t idx = ((size_t)b * S_ + q0 + q) * D_ + h * HD_ + d;
        unsigned short hh = f2bf(s);
        AOhi[idx] = hh;
        AOlo[idx] = f2bf(s - bf2f(hh));
    }
}

extern "C" void kernel_launch(void* const* d_in, const int* in_sizes, int n_in,
                              void* d_out, int out_size, void* d_ws, size_t ws_size,
                              hipStream_t stream) {
    const float* x  = (const float*)d_in[0];
    const float* Wq = (const float*)d_in[1];
    const float* bq = (const float*)d_in[2];
    const float* Wk = (const float*)d_in[3];
    const float* bk = (const float*)d_in[4];
    const float* Wv = (const float*)d_in[5];
    const float* bv = (const float*)d_in[6];
    const float* Wo = (const float*)d_in[7];
    const float* bo = (const float*)d_in[8];
    float* out = (float*)d_out;

    const size_t NP = (size_t)M_ * D_;      // 3,145,728 elems
    const size_t NW = (size_t)D_ * D_;      // 589,824 elems
    unsigned short* p = (unsigned short*)d_ws;
    unsigned short* xhi = p;  p += NP;
    unsigned short* xlo = p;  p += NP;
    unsigned short* Wqh = p;  p += NW;  unsigned short* Wql = p;  p += NW;
    unsigned short* Wkh = p;  p += NW;  unsigned short* Wkl = p;  p += NW;
    unsigned short* Wvh = p;  p += NW;  unsigned short* Wvl = p;  p += NW;
    unsigned short* Woh = p;  p += NW;  unsigned short* Wol = p;  p += NW;
    unsigned short* Qh  = p;  p += NP;  unsigned short* Ql  = p;  p += NP;
    unsigned short* Kh  = p;  p += NP;  unsigned short* Kl  = p;  p += NP;
    unsigned short* Vth = p;  p += NP;  unsigned short* Vtl = p;  p += NP;
    // AO planes alias x planes (x dead after the V projection)
    unsigned short* AOh = xhi;
    unsigned short* AOl = xlo;

    split_kernel<<<(int)((NP + 255) / 256), 256, 0, stream>>>(x,  xhi, xlo, (int)NP);
    split_kernel<<<(int)((NW + 255) / 256), 256, 0, stream>>>(Wq, Wqh, Wql, (int)NW);
    split_kernel<<<(int)((NW + 255) / 256), 256, 0, stream>>>(Wk, Wkh, Wkl, (int)NW);
    split_kernel<<<(int)((NW + 255) / 256), 256, 0, stream>>>(Wv, Wvh, Wvl, (int)NW);
    split_kernel<<<(int)((NW + 255) / 256), 256, 0, stream>>>(Wo, Woh, Wol, (int)NW);

    dim3 g(M_ / 128, D_ / 64);              // (32, 12)
    gemm_bf16s<1><<<g, 256, 0, stream>>>(xhi, xlo, Wqh, Wql, bq, nullptr, Qh, Ql);
    gemm_bf16s<1><<<g, 256, 0, stream>>>(xhi, xlo, Wkh, Wkl, bk, nullptr, Kh, Kl);
    gemm_bf16s<2><<<g, 256, 0, stream>>>(xhi, xlo, Wvh, Wvl, bv, nullptr, Vth, Vtl);

    attn_kernel<<<(S_ / 16) * B_ * H_, 512, 0, stream>>>(Qh, Ql, Kh, Kl, Vth, Vtl, AOh, AOl);

    gemm_bf16s<0><<<g, 256, 0, stream>>>(AOh, AOl, Woh, Wol, bo, out, nullptr, nullptr);
}

// Round 4
// 640.258 us; speedup vs baseline: 6.5290x; 1.2473x over previous
//
#include <hip/hip_runtime.h>
#include <math.h>

#define B_ 2
#define S_ 2048
#define D_ 768
#define H_ 12
#define HD_ 64
#define KKEEP 614            // max(1, int(0.3*2048))
#define M_ (B_*S_)           // 4096
#define KD_ 768

typedef __attribute__((ext_vector_type(8))) short bf8;   // 8 bf16 = 4 VGPR (MFMA A/B frag)
typedef __attribute__((ext_vector_type(4))) float f4;    // MFMA 16x16 C/D frag

__device__ __forceinline__ unsigned short f2bf(float f) {   // RNE fp32->bf16
    unsigned u = __float_as_uint(f);
    u += 0x7FFF + ((u >> 16) & 1);
    return (unsigned short)(u >> 16);
}
__device__ __forceinline__ float bf2f(unsigned short h) {
    return __uint_as_float((unsigned)h << 16);
}
__device__ __forceinline__ unsigned orderable(float f) {
    unsigned b = __float_as_uint(f);
    return (b & 0x80000000u) ? ~b : (b | 0x80000000u);
}

// fp32 -> (bf16 hi, bf16 lo) planes; a = hi + lo to ~16 mantissa bits
__global__ void split_kernel(const float* __restrict__ src,
                             unsigned short* __restrict__ hi,
                             unsigned short* __restrict__ lo, int n) {
    int i = blockIdx.x * blockDim.x + threadIdx.x;
    int stride = gridDim.x * blockDim.x;
    for (; i < n; i += stride) {
        float f = src[i];
        unsigned short h = f2bf(f);
        hi[i] = h;
        lo[i] = f2bf(f - bf2f(h));
    }
}

// C[m][n] = sum_k A[m][k]*W[n][k] + bias[n], split-bf16 (3 MFMA per product).
// Tile 128(M) x 64(N), BK=32, 256 thr = 4 waves, wave owns 32-row strip.
// MODE 0: fp32 out[m*768+n]
// MODE 1: bf16 hi/lo planes, BHSD  [b][h][s][d]   (Q, K)
// MODE 2: bf16 hi/lo planes, BHDS  [b][h][d][s]   (V transposed)
template<int MODE>
__global__ __launch_bounds__(256)
void gemm_bf16s(const unsigned short* __restrict__ Ahi, const unsigned short* __restrict__ Alo,
                const unsigned short* __restrict__ Whi, const unsigned short* __restrict__ Wlo,
                const float* __restrict__ bias,
                float* __restrict__ outf,
                unsigned short* __restrict__ ohi, unsigned short* __restrict__ olo) {
    __shared__ unsigned short Ah[128][32], Al[128][32], Bh[64][32], Bl[64][32];  // 24KB
    const int bm = blockIdx.x * 128, bn = blockIdx.y * 64;
    const int tid = threadIdx.x, lane = tid & 63, wave = tid >> 6;
    const int col = lane & 15, quad = lane >> 4;

    f4 acc[2][4];
#pragma unroll
    for (int mi = 0; mi < 2; ++mi)
#pragma unroll
        for (int ni = 0; ni < 4; ++ni) { f4 z = {0.f,0.f,0.f,0.f}; acc[mi][ni] = z; }

    for (int kt = 0; kt < KD_; kt += 32) {
        __syncthreads();
#pragma unroll
        for (int c = 0; c < 2; ++c) {
            int idx = c * 256 + tid;
            int row = idx >> 2, ko = (idx & 3) * 8;
            *(uint4*)&Ah[row][ko] = *(const uint4*)&Ahi[(size_t)(bm + row) * KD_ + kt + ko];
            *(uint4*)&Al[row][ko] = *(const uint4*)&Alo[(size_t)(bm + row) * KD_ + kt + ko];
        }
        {
            int row = tid >> 2, ko = (tid & 3) * 8;
            *(uint4*)&Bh[row][ko] = *(const uint4*)&Whi[(size_t)(bn + row) * KD_ + kt + ko];
            *(uint4*)&Bl[row][ko] = *(const uint4*)&Wlo[(size_t)(bn + row) * KD_ + kt + ko];
        }
        __syncthreads();

        bf8 af[2][2], wf[4][2];
#pragma unroll
        for (int mi = 0; mi < 2; ++mi) {
            int r = wave * 32 + mi * 16 + col;
            af[mi][0] = *(const bf8*)&Ah[r][quad * 8];
            af[mi][1] = *(const bf8*)&Al[r][quad * 8];
        }
#pragma unroll
        for (int ni = 0; ni < 4; ++ni) {
            int r = ni * 16 + col;
            wf[ni][0] = *(const bf8*)&Bh[r][quad * 8];
            wf[ni][1] = *(const bf8*)&Bl[r][quad * 8];
        }
#pragma unroll
        for (int mi = 0; mi < 2; ++mi)
#pragma unroll
            for (int ni = 0; ni < 4; ++ni) {
                acc[mi][ni] = __builtin_amdgcn_mfma_f32_16x16x32_bf16(af[mi][0], wf[ni][0], acc[mi][ni], 0, 0, 0);
                acc[mi][ni] = __builtin_amdgcn_mfma_f32_16x16x32_bf16(af[mi][1], wf[ni][0], acc[mi][ni], 0, 0, 0);
                acc[mi][ni] = __builtin_amdgcn_mfma_f32_16x16x32_bf16(af[mi][0], wf[ni][1], acc[mi][ni], 0, 0, 0);
            }
    }

    float bv[4];
#pragma unroll
    for (int ni = 0; ni < 4; ++ni) bv[ni] = bias[bn + ni * 16 + col];
#pragma unroll
    for (int mi = 0; mi < 2; ++mi)
#pragma unroll
        for (int ni = 0; ni < 4; ++ni)
#pragma unroll
            for (int r = 0; r < 4; ++r) {
                int m = bm + wave * 32 + mi * 16 + quad * 4 + r;  // C row = quad*4+reg
                int n = bn + ni * 16 + col;                       // C col = lane&15
                float v = acc[mi][ni][r] + bv[ni];
                if (MODE == 0) {
                    outf[(size_t)m * D_ + n] = v;
                } else {
                    int b = m >> 11, s = m & 2047, h = n >> 6, d = n & 63;
                    size_t idx = (MODE == 1)
                        ? ((((size_t)b * H_ + h) * S_ + s) * HD_ + d)
                        : ((((size_t)b * H_ + h) * HD_ + d) * S_ + s);
                    unsigned short hh = f2bf(v);
                    ohi[idx] = hh;
                    olo[idx] = f2bf(v - bf2f(hh));
                }
            }
}

// Attention: block = 16 q rows of one (b,h); 1024 thr = 16 waves; wave owns 128 keys.
// Scores via split-bf16 MFMA into C-layout regs (32 fp32/lane), exact radix top-k
// (hist stride 257 -> conflict-spread), softmax, PV via single-MFMA bf16 (P hi, V hi).
__global__ __launch_bounds__(1024, 4)
void attn_kernel(const unsigned short* __restrict__ Qhi, const unsigned short* __restrict__ Qlo,
                 const unsigned short* __restrict__ Khi, const unsigned short* __restrict__ Klo,
                 const unsigned short* __restrict__ Vthi,
                 unsigned short* __restrict__ AOhi, unsigned short* __restrict__ AOlo) {
    const int bid = blockIdx.x;            // 3072 = 24 bh * 128 q-tiles
    const int xcd = bid & 7, sub = (bid >> 3) % 3, tile = bid / 24;
    const int bh = xcd * 3 + sub;          // L2 locality: 3 (b,h) per XCD
    const int b = bh / H_, h = bh % H_;
    const int q0 = tile * 16;
    const int tid = threadIdx.x, lane = tid & 63, wave = tid >> 6;   // wave 0..15
    const int col = lane & 15, quad = lane >> 4;

    __shared__ float osum[8][16][64];                 // 32KB; aliased as hist early
    int (*hist)[257] = (int(*)[257])osum;             // stride 257: bank=(row+bin)%32
    __shared__ unsigned short Pscr[16][16][32];       // 16KB: per-wave P-hi bounce
    __shared__ float partial[16][16];
    __shared__ float mrow[16], linv[16];
    __shared__ unsigned prefix[16];
    __shared__ int kkarr[16];

    for (int z = tid; z < 16 * 257; z += 1024) ((int*)hist)[z] = 0;
    if (tid < 16) { prefix[tid] = 0u; kkarr[tid] = KKEEP; }

    // Q A-frags direct from global: m = col = q-local, k = quad*8+j
    const size_t qbase = ((size_t)bh * S_ + q0 + col) * HD_;
    bf8 qh0 = *(const bf8*)&Qhi[qbase + quad * 8];
    bf8 qh1 = *(const bf8*)&Qhi[qbase + 32 + quad * 8];
    bf8 ql0 = *(const bf8*)&Qlo[qbase + quad * 8];
    bf8 ql1 = *(const bf8*)&Qlo[qbase + 32 + quad * 8];
    __syncthreads();   // hist zero visible

    // ---- QK^T: sc[t][r] : q = quad*4+r, key = wave*128 + t*16 + col ----
    float sc[8][4];
    const size_t kbb = (size_t)bh * S_ * HD_;
#pragma unroll
    for (int t = 0; t < 8; ++t) {
        const size_t kr = kbb + (size_t)(wave * 128 + t * 16 + col) * HD_;
        bf8 kh0 = *(const bf8*)&Khi[kr + quad * 8];
        bf8 kh1 = *(const bf8*)&Khi[kr + 32 + quad * 8];
        bf8 kl0 = *(const bf8*)&Klo[kr + quad * 8];
        bf8 kl1 = *(const bf8*)&Klo[kr + 32 + quad * 8];
        f4 a = {0.f, 0.f, 0.f, 0.f};
        a = __builtin_amdgcn_mfma_f32_16x16x32_bf16(qh0, kh0, a, 0, 0, 0);
        a = __builtin_amdgcn_mfma_f32_16x16x32_bf16(qh1, kh1, a, 0, 0, 0);
        a = __builtin_amdgcn_mfma_f32_16x16x32_bf16(ql0, kh0, a, 0, 0, 0);
        a = __builtin_amdgcn_mfma_f32_16x16x32_bf16(ql1, kh1, a, 0, 0, 0);
        a = __builtin_amdgcn_mfma_f32_16x16x32_bf16(qh0, kl0, a, 0, 0, 0);
        a = __builtin_amdgcn_mfma_f32_16x16x32_bf16(qh1, kl1, a, 0, 0, 0);
        sc[t][0] = a[0] * 0.125f; sc[t][1] = a[1] * 0.125f;
        sc[t][2] = a[2] * 0.125f; sc[t][3] = a[3] * 0.125f;
    }

    // ---- per-row max: local -> shfl over the 16-lane col group ----
    {
        float mq[4] = {-1e30f, -1e30f, -1e30f, -1e30f};
#pragma unroll
        for (int t = 0; t < 8; ++t)
#pragma unroll
            for (int r = 0; r < 4; ++r) mq[r] = fmaxf(mq[r], sc[t][r]);
#pragma unroll
        for (int off = 8; off >= 1; off >>= 1)
#pragma unroll
            for (int r = 0; r < 4; ++r) mq[r] = fmaxf(mq[r], __shfl_xor(mq[r], off, 64));
        if (col == 0)
#pragma unroll
            for (int r = 0; r < 4; ++r) partial[wave][quad * 4 + r] = mq[r];
    }
    // ---- pass-3 histogram (top byte of orderable score) ----
#pragma unroll
    for (int t = 0; t < 8; ++t)
#pragma unroll
        for (int r = 0; r < 4; ++r)
            atomicAdd(&hist[quad * 4 + r][orderable(sc[t][r]) >> 24], 1);
    __syncthreads();
    if (tid < 16) {
        float m = partial[0][tid];
        for (int w = 1; w < 16; ++w) m = fmaxf(m, partial[w][tid]);
        mrow[tid] = m;
    }

    // ---- exact 614th-largest threshold: 4-pass radix select (wave w scans row w) ----
    const unsigned hmasks[4] = {0xFFFFFF00u, 0xFFFF0000u, 0xFF000000u, 0u};
    for (int p = 3; p >= 0; --p) {
        int shift = p * 8;
        {
            const int r = wave;
            int h0 = hist[r][lane * 4 + 0], h1 = hist[r][lane * 4 + 1];
            int h2 = hist[r][lane * 4 + 2], h3 = hist[r][lane * 4 + 3];
            int s3 = h3, s2 = h2 + s3, s1 = h1 + s2, s0 = h0 + s1;
            int x = s0;
#pragma unroll
            for (int off = 1; off < 64; off <<= 1) {
                int v = __shfl_down(x, off, 64);
                if (lane + off < 64) x += v;
            }
            int A = x - s0;
            int kk = kkarr[r];
            int suf[4] = { s0 + A, s1 + A, s2 + A, s3 + A };
            int nxt[4] = { s1 + A, s2 + A, s3 + A, A };
#pragma unroll
            for (int i = 0; i < 4; ++i)
                if (suf[i] >= kk && nxt[i] < kk) {       // exactly one (lane,i)
                    prefix[r] |= (unsigned)(lane * 4 + i) << shift;
                    kkarr[r] = kk - nxt[i];
                }
            hist[r][lane * 4 + 0] = 0; hist[r][lane * 4 + 1] = 0;
            hist[r][lane * 4 + 2] = 0; hist[r][lane * 4 + 3] = 0;
        }
        __syncthreads();
        if (p == 0) break;
        unsigned pr[4];
#pragma unroll
        for (int r = 0; r < 4; ++r) pr[r] = prefix[quad * 4 + r];
        unsigned hm = hmasks[p - 1];
        int sh = (p - 1) * 8;
#pragma unroll
        for (int t = 0; t < 8; ++t)
#pragma unroll
            for (int r = 0; r < 4; ++r) {
                unsigned u = orderable(sc[t][r]);
                if (((u ^ pr[r]) & hm) == 0)
                    atomicAdd(&hist[quad * 4 + r][(u >> sh) & 255], 1);
            }
        __syncthreads();
    }

    // ---- masked softmax weights + row sum ----
    {
        unsigned Tu[4]; float mr[4], ls[4];
#pragma unroll
        for (int r = 0; r < 4; ++r) {
            Tu[r] = prefix[quad * 4 + r];
            mr[r] = mrow[quad * 4 + r];
            ls[r] = 0.f;
        }
#pragma unroll
        for (int t = 0; t < 8; ++t)
#pragma unroll
            for (int r = 0; r < 4; ++r) {
                float s = sc[t][r];
                float w = (orderable(s) >= Tu[r]) ? __expf(s - mr[r]) : 0.f;
                sc[t][r] = w;
                ls[r] += w;
            }
#pragma unroll
        for (int off = 8; off >= 1; off >>= 1)
#pragma unroll
            for (int r = 0; r < 4; ++r) ls[r] += __shfl_xor(ls[r], off, 64);
        if (col == 0)
#pragma unroll
            for (int r = 0; r < 4; ++r) partial[wave][quad * 4 + r] = ls[r];
    }
    __syncthreads();
    if (tid < 16) {
        float l = 0.f;
        for (int w = 0; w < 16; ++w) l += partial[w][tid];
        linv[tid] = 1.f / l;
    }

    // ---- PV (bf16 P-hi x V-hi): bounce P C-layout -> A-layout via per-wave LDS ----
    f4 od[4];
#pragma unroll
    for (int dt = 0; dt < 4; ++dt) { f4 z = {0.f,0.f,0.f,0.f}; od[dt] = z; }
    const size_t vbb = (size_t)bh * HD_ * S_;
#pragma unroll
    for (int c = 0; c < 4; ++c) {
#pragma unroll
        for (int tt = 0; tt < 2; ++tt) {
            int t = c * 2 + tt;
#pragma unroll
            for (int r = 0; r < 4; ++r)
                Pscr[wave][quad * 4 + r][tt * 16 + col] = f2bf(sc[t][r]);
        }
        // same-wave cross-lane LDS RAW: compiler inserts lgkmcnt wait
        bf8 ph = *(const bf8*)&Pscr[wave][col][quad * 8];
        const size_t sbase = (size_t)(wave * 128 + c * 32 + quad * 8);
#pragma unroll
        for (int dt = 0; dt < 4; ++dt) {
            bf8 vh = *(const bf8*)&Vthi[vbb + (size_t)(dt * 16 + col) * S_ + sbase];
            od[dt] = __builtin_amdgcn_mfma_f32_16x16x32_bf16(ph, vh, od[dt], 0, 0, 0);
        }
    }
    // paired reduction into 8 slots (osum aliases dead hist; last use was p==0 scan)
    if (wave < 8) {
#pragma unroll
        for (int dt = 0; dt < 4; ++dt)
#pragma unroll
            for (int r = 0; r < 4; ++r)
                osum[wave][quad * 4 + r][dt * 16 + col] = od[dt][r];
    }
    __syncthreads();
    if (wave >= 8) {
#pragma unroll
        for (int dt = 0; dt < 4; ++dt)
#pragma unroll
            for (int r = 0; r < 4; ++r)
                osum[wave - 8][quad * 4 + r][dt * 16 + col] += od[dt][r];
    }
    __syncthreads();

    // ---- final: 1024 threads cover 16x64 (q,d); normalize, emit hi/lo planes ----
    {
        int q = tid >> 6, d = tid & 63;
        float s = 0.f;
#pragma unroll
        for (int w = 0; w < 8; ++w) s += osum[w][q][d];
        s *= linv[q];
        size_t idx = ((size_t)b * S_ + q0 + q) * D_ + h * HD_ + d;
        unsigned short hh = f2bf(s);
        AOhi[idx] = hh;
        AOlo[idx] = f2bf(s - bf2f(hh));
    }
}

extern "C" void kernel_launch(void* const* d_in, const int* in_sizes, int n_in,
                              void* d_out, int out_size, void* d_ws, size_t ws_size,
                              hipStream_t stream) {
    const float* x  = (const float*)d_in[0];
    const float* Wq = (const float*)d_in[1];
    const float* bq = (const float*)d_in[2];
    const float* Wk = (const float*)d_in[3];
    const float* bk = (const float*)d_in[4];
    const float* Wv = (const float*)d_in[5];
    const float* bv = (const float*)d_in[6];
    const float* Wo = (const float*)d_in[7];
    const float* bo = (const float*)d_in[8];
    float* out = (float*)d_out;

    const size_t NP = (size_t)M_ * D_;      // 3,145,728 elems
    const size_t NW = (size_t)D_ * D_;      // 589,824 elems
    unsigned short* p = (unsigned short*)d_ws;
    unsigned short* xhi = p;  p += NP;
    unsigned short* xlo = p;  p += NP;
    unsigned short* Wqh = p;  p += NW;  unsigned short* Wql = p;  p += NW;
    unsigned short* Wkh = p;  p += NW;  unsigned short* Wkl = p;  p += NW;
    unsigned short* Wvh = p;  p += NW;  unsigned short* Wvl = p;  p += NW;
    unsigned short* Woh = p;  p += NW;  unsigned short* Wol = p;  p += NW;
    unsigned short* Qh  = p;  p += NP;  unsigned short* Ql  = p;  p += NP;
    unsigned short* Kh  = p;  p += NP;  unsigned short* Kl  = p;  p += NP;
    unsigned short* Vth = p;  p += NP;  unsigned short* Vtl = p;  p += NP;
    // AO planes alias x planes (x dead after the V projection)
    unsigned short* AOh = xhi;
    unsigned short* AOl = xlo;

    split_kernel<<<(int)((NP + 255) / 256), 256, 0, stream>>>(x,  xhi, xlo, (int)NP);
    split_kernel<<<(int)((NW + 255) / 256), 256, 0, stream>>>(Wq, Wqh, Wql, (int)NW);
    split_kernel<<<(int)((NW + 255) / 256), 256, 0, stream>>>(Wk, Wkh, Wkl, (int)NW);
    split_kernel<<<(int)((NW + 255) / 256), 256, 0, stream>>>(Wv, Wvh, Wvl, (int)NW);
    split_kernel<<<(int)((NW + 255) / 256), 256, 0, stream>>>(Wo, Woh, Wol, (int)NW);

    dim3 g(M_ / 128, D_ / 64);              // (32, 12)
    gemm_bf16s<1><<<g, 256, 0, stream>>>(xhi, xlo, Wqh, Wql, bq, nullptr, Qh, Ql);
    gemm_bf16s<1><<<g, 256, 0, stream>>>(xhi, xlo, Wkh, Wkl, bk, nullptr, Kh, Kl);
    gemm_bf16s<2><<<g, 256, 0, stream>>>(xhi, xlo, Wvh, Wvl, bv, nullptr, Vth, Vtl);

    attn_kernel<<<(S_ / 16) * B_ * H_, 1024, 0, stream>>>(Qh, Ql, Kh, Kl, Vth, AOh, AOl);

    gemm_bf16s<0><<<g, 256, 0, stream>>>(AOh, AOl, Woh, Wol, bo, out, nullptr, nullptr);
}

// Round 5
// 545.802 us; speedup vs baseline: 7.6589x; 1.1731x over previous
//
#include <hip/hip_runtime.h>
#include <math.h>

#define B_ 2
#define S_ 2048
#define D_ 768
#define H_ 12
#define HD_ 64
#define KKEEP 614            // max(1, int(0.3*2048))
#define M_ (B_*S_)           // 4096
#define KD_ 768
#define SDW 1036             // scB row stride in dwords (16B-aligned rows: 4144B)
#define SRW 2072             // scB row stride in ushorts

typedef __attribute__((ext_vector_type(8))) short bf8;   // 8 bf16 = 4 VGPR (MFMA A/B frag)
typedef __attribute__((ext_vector_type(4))) float f4;    // MFMA 16x16 C/D frag

__device__ __forceinline__ unsigned short f2bf(float f) {   // RNE fp32->bf16
    unsigned u = __float_as_uint(f);
    u += 0x7FFF + ((u >> 16) & 1);
    return (unsigned short)(u >> 16);
}
__device__ __forceinline__ float bf2f(unsigned short h) {
    return __uint_as_float((unsigned)h << 16);
}
__device__ __forceinline__ unsigned ord16(unsigned short h) {   // bf16 -> orderable u16
    return (h & 0x8000u) ? ((~(unsigned)h) & 0xFFFFu) : ((unsigned)h | 0x8000u);
}
__device__ __forceinline__ unsigned short inv16(unsigned o) {   // orderable u16 -> bf16
    return (unsigned short)((o & 0x8000u) ? (o & 0x7FFFu) : ((~o) & 0xFFFFu));
}

// fp32 -> (bf16 hi, bf16 lo) planes; a = hi + lo to ~16 mantissa bits
__global__ void split_kernel(const float* __restrict__ src,
                             unsigned short* __restrict__ hi,
                             unsigned short* __restrict__ lo, int n) {
    int i = blockIdx.x * blockDim.x + threadIdx.x;
    int stride = gridDim.x * blockDim.x;
    for (; i < n; i += stride) {
        float f = src[i];
        unsigned short h = f2bf(f);
        hi[i] = h;
        lo[i] = f2bf(f - bf2f(h));
    }
}

// C[m][n] = sum_k A[m][k]*W[n][k] + bias[n], split-bf16 (3 MFMA per product).
// MODE 0: fp32 out[m*768+n]
// MODE 1: bf16 planes, BHSD  [b][h][s][d]   (Q, K)
// MODE 2: bf16 planes, BHDS  [b][h][d][s]   (V transposed)
// WLO: write the lo plane too (needed only for Q and the AO->final path)
template<int MODE, int WLO>
__global__ __launch_bounds__(256)
void gemm_bf16s(const unsigned short* __restrict__ Ahi, const unsigned short* __restrict__ Alo,
                const unsigned short* __restrict__ Whi, const unsigned short* __restrict__ Wlo,
                const float* __restrict__ bias,
                float* __restrict__ outf,
                unsigned short* __restrict__ ohi, unsigned short* __restrict__ olo) {
    __shared__ unsigned short Ah[128][32], Al[128][32], Bh[64][32], Bl[64][32];  // 24KB
    const int bm = blockIdx.x * 128, bn = blockIdx.y * 64;
    const int tid = threadIdx.x, lane = tid & 63, wave = tid >> 6;
    const int col = lane & 15, quad = lane >> 4;

    f4 acc[2][4];
#pragma unroll
    for (int mi = 0; mi < 2; ++mi)
#pragma unroll
        for (int ni = 0; ni < 4; ++ni) { f4 z = {0.f,0.f,0.f,0.f}; acc[mi][ni] = z; }

    for (int kt = 0; kt < KD_; kt += 32) {
        __syncthreads();
#pragma unroll
        for (int c = 0; c < 2; ++c) {
            int idx = c * 256 + tid;
            int row = idx >> 2, ko = (idx & 3) * 8;
            *(uint4*)&Ah[row][ko] = *(const uint4*)&Ahi[(size_t)(bm + row) * KD_ + kt + ko];
            *(uint4*)&Al[row][ko] = *(const uint4*)&Alo[(size_t)(bm + row) * KD_ + kt + ko];
        }
        {
            int row = tid >> 2, ko = (tid & 3) * 8;
            *(uint4*)&Bh[row][ko] = *(const uint4*)&Whi[(size_t)(bn + row) * KD_ + kt + ko];
            *(uint4*)&Bl[row][ko] = *(const uint4*)&Wlo[(size_t)(bn + row) * KD_ + kt + ko];
        }
        __syncthreads();

        bf8 af[2][2], wf[4][2];
#pragma unroll
        for (int mi = 0; mi < 2; ++mi) {
            int r = wave * 32 + mi * 16 + col;
            af[mi][0] = *(const bf8*)&Ah[r][quad * 8];
            af[mi][1] = *(const bf8*)&Al[r][quad * 8];
        }
#pragma unroll
        for (int ni = 0; ni < 4; ++ni) {
            int r = ni * 16 + col;
            wf[ni][0] = *(const bf8*)&Bh[r][quad * 8];
            wf[ni][1] = *(const bf8*)&Bl[r][quad * 8];
        }
#pragma unroll
        for (int mi = 0; mi < 2; ++mi)
#pragma unroll
            for (int ni = 0; ni < 4; ++ni) {
                acc[mi][ni] = __builtin_amdgcn_mfma_f32_16x16x32_bf16(af[mi][0], wf[ni][0], acc[mi][ni], 0, 0, 0);
                acc[mi][ni] = __builtin_amdgcn_mfma_f32_16x16x32_bf16(af[mi][1], wf[ni][0], acc[mi][ni], 0, 0, 0);
                acc[mi][ni] = __builtin_amdgcn_mfma_f32_16x16x32_bf16(af[mi][0], wf[ni][1], acc[mi][ni], 0, 0, 0);
            }
    }

    float bv[4];
#pragma unroll
    for (int ni = 0; ni < 4; ++ni) bv[ni] = bias[bn + ni * 16 + col];
#pragma unroll
    for (int mi = 0; mi < 2; ++mi)
#pragma unroll
        for (int ni = 0; ni < 4; ++ni)
#pragma unroll
            for (int r = 0; r < 4; ++r) {
                int m = bm + wave * 32 + mi * 16 + quad * 4 + r;  // C row = quad*4+reg
                int n = bn + ni * 16 + col;                       // C col = lane&15
                float v = acc[mi][ni][r] + bv[ni];
                if (MODE == 0) {
                    outf[(size_t)m * D_ + n] = v;
                } else {
                    int b = m >> 11, s = m & 2047, h = n >> 6, d = n & 63;
                    size_t idx = (MODE == 1)
                        ? ((((size_t)b * H_ + h) * S_ + s) * HD_ + d)
                        : ((((size_t)b * H_ + h) * HD_ + d) * S_ + s);
                    unsigned short hh = f2bf(v);
                    ohi[idx] = hh;
                    if (WLO) olo[idx] = f2bf(v - bf2f(hh));
                }
            }
}

// Attention: block = 16 q rows of one (b,h); 1024 thr = 16 waves; wave owns 128 keys.
// QK via 4-MFMA split-bf16 -> scores packed as orderable-u16 (2/reg). LDS transpose
// puts each full row in one wave; exact-on-bf16 top-k threshold via 16-iter binary
// search (registers+shuffles only, NO atomics). Weights stored bf16 in scB; PV MFMA
// reads A-frags from scB via b128. osum aliases scB after PV.
__global__ __launch_bounds__(1024, 8)
void attn_kernel(const unsigned short* __restrict__ Qhi, const unsigned short* __restrict__ Qlo,
                 const unsigned short* __restrict__ Khi,
                 const unsigned short* __restrict__ Vthi,
                 unsigned short* __restrict__ AOhi, unsigned short* __restrict__ AOlo) {
    const int bid = blockIdx.x;            // 3072 = 24 bh * 128 q-tiles
    const int xcd = bid & 7, sub = (bid >> 3) % 3, tile = bid / 24;
    const int bh = xcd * 3 + sub;          // L2 locality: 3 (b,h) per XCD
    const int b = bh / H_, h = bh % H_;
    const int q0 = tile * 16;
    const int tid = threadIdx.x, lane = tid & 63, wave = tid >> 6;   // wave 0..15
    const int col = lane & 15, quad = lane >> 4;

    __shared__ __align__(16) unsigned char arena[16 * 4144];   // 66.3KB: scB / osum alias
    unsigned short* scB = (unsigned short*)arena;              // [16][2072] bf16
    float (*osum)[16][64] = (float (*)[16][64])arena;          // [8][16][64] f32 (32KB)
    __shared__ float partial[16][16];
    __shared__ float mrowf[16], linv[16];
    __shared__ unsigned Tsh[16];

    // Q A-frags direct from global: m = col = q-local, k = quad*8+j
    const size_t qbase = ((size_t)bh * S_ + q0 + col) * HD_;
    bf8 qh0 = *(const bf8*)&Qhi[qbase + quad * 8];
    bf8 qh1 = *(const bf8*)&Qhi[qbase + 32 + quad * 8];
    bf8 ql0 = *(const bf8*)&Qlo[qbase + quad * 8];
    bf8 ql1 = *(const bf8*)&Qlo[qbase + 32 + quad * 8];

    // ---- QK^T (4-MFMA split): q = quad*4+r, key = wave*128 + t*16 + col ----
    // Scores leave as orderable-u16, packed 2 per dword: ok[t][r>>1]
    unsigned ok[8][2];
    const size_t kbb = (size_t)bh * S_ * HD_;
#pragma unroll
    for (int t = 0; t < 8; ++t) {
        const size_t kr = kbb + (size_t)(wave * 128 + t * 16 + col) * HD_;
        bf8 kh0 = *(const bf8*)&Khi[kr + quad * 8];
        bf8 kh1 = *(const bf8*)&Khi[kr + 32 + quad * 8];
        f4 a = {0.f, 0.f, 0.f, 0.f};
        a = __builtin_amdgcn_mfma_f32_16x16x32_bf16(qh0, kh0, a, 0, 0, 0);
        a = __builtin_amdgcn_mfma_f32_16x16x32_bf16(qh1, kh1, a, 0, 0, 0);
        a = __builtin_amdgcn_mfma_f32_16x16x32_bf16(ql0, kh0, a, 0, 0, 0);
        a = __builtin_amdgcn_mfma_f32_16x16x32_bf16(ql1, kh1, a, 0, 0, 0);
        unsigned o0 = ord16(f2bf(a[0] * 0.125f));
        unsigned o1 = ord16(f2bf(a[1] * 0.125f));
        unsigned o2 = ord16(f2bf(a[2] * 0.125f));
        unsigned o3 = ord16(f2bf(a[3] * 0.125f));
        ok[t][0] = o0 | (o1 << 16);
        ok[t][1] = o2 | (o3 << 16);
    }

    // ---- transpose scores into scB[row][key] (b16 stores, ~4-way worst) ----
#pragma unroll
    for (int t = 0; t < 8; ++t)
#pragma unroll
        for (int r = 0; r < 4; ++r) {
            unsigned o = (ok[t][r >> 1] >> ((r & 1) * 16)) & 0xFFFFu;
            scB[(quad * 4 + r) * SRW + wave * 128 + t * 16 + col] = (unsigned short)o;
        }
    __syncthreads();                                       // [1] transpose visible

    // ---- wave w owns row w: strided conflict-free dword reads ----
    unsigned kv[16];
    {
        const unsigned* rowp = (const unsigned*)(arena + wave * 4144);
#pragma unroll
        for (int j = 0; j < 16; ++j) kv[j] = rowp[lane + 64 * j];
    }
    // row max (orderable space)
    unsigned mo = 0;
#pragma unroll
    for (int j = 0; j < 16; ++j) {
        unsigned hi = kv[j] >> 16, lo = kv[j] & 0xFFFFu;
        mo = mo > hi ? mo : hi;
        mo = mo > lo ? mo : lo;
    }
#pragma unroll
    for (int off = 1; off < 64; off <<= 1) {
        unsigned v = __shfl_xor((int)mo, off, 64);
        mo = mo > v ? mo : v;
    }
    // binary search: largest T16 with count(>=T16) >= KKEEP  (T16 = 614th largest)
    unsigned T = 0;
#pragma unroll
    for (int bit = 15; bit >= 0; --bit) {
        unsigned cand = T | (1u << bit);
        int cnt = 0;
#pragma unroll
        for (int j = 0; j < 16; ++j)
            cnt += (int)((kv[j] >> 16) >= cand) + (int)((kv[j] & 0xFFFFu) >= cand);
#pragma unroll
        for (int off = 1; off < 64; off <<= 1) cnt += __shfl_xor(cnt, off, 64);
        if (cnt >= KKEEP) T = cand;
    }
    if (lane == 0) {
        Tsh[wave] = T;
        mrowf[wave] = bf2f(inv16(mo));
    }
    __syncthreads();                                       // [2] T,m visible

    // ---- weights: w = exp(s-m) if key >= T else 0; store bf16 into scB ----
    {
        unsigned Tq[4]; float mr[4], ls[4];
#pragma unroll
        for (int r = 0; r < 4; ++r) {
            Tq[r] = Tsh[quad * 4 + r];
            mr[r] = mrowf[quad * 4 + r];
            ls[r] = 0.f;
        }
#pragma unroll
        for (int t = 0; t < 8; ++t)
#pragma unroll
            for (int r = 0; r < 4; ++r) {
                unsigned o = (ok[t][r >> 1] >> ((r & 1) * 16)) & 0xFFFFu;
                float w = 0.f;
                if (o >= Tq[r]) w = __expf(bf2f(inv16(o)) - mr[r]);
                ls[r] += w;
                scB[(quad * 4 + r) * SRW + wave * 128 + t * 16 + col] = f2bf(w);
            }
#pragma unroll
        for (int off = 1; off < 16; off <<= 1)
#pragma unroll
            for (int r = 0; r < 4; ++r) ls[r] += __shfl_xor(ls[r], off, 64);
        if (col == 0)
#pragma unroll
            for (int r = 0; r < 4; ++r) partial[wave][quad * 4 + r] = ls[r];
    }
    __syncthreads();                                       // [3] weights + partials
    if (tid < 16) {
        float l = 0.f;
#pragma unroll
        for (int w = 0; w < 16; ++w) l += partial[w][tid];
        linv[tid] = 1.f / l;   // visible to all via barrier [4]/[5]
    }

    // ---- PV: A-frags (P) from scB via b128; B-frags (V^T) from global ----
    f4 od[4];
#pragma unroll
    for (int dt = 0; dt < 4; ++dt) { f4 z = {0.f,0.f,0.f,0.f}; od[dt] = z; }
    const size_t vbb = (size_t)bh * HD_ * S_;
#pragma unroll
    for (int c = 0; c < 4; ++c) {
        bf8 ph = *(const bf8*)&scB[col * SRW + wave * 128 + c * 32 + quad * 8];
        const size_t sbase = (size_t)(wave * 128 + c * 32 + quad * 8);
#pragma unroll
        for (int dt = 0; dt < 4; ++dt) {
            bf8 vh = *(const bf8*)&Vthi[vbb + (size_t)(dt * 16 + col) * S_ + sbase];
            od[dt] = __builtin_amdgcn_mfma_f32_16x16x32_bf16(ph, vh, od[dt], 0, 0, 0);
        }
    }
    __syncthreads();                                       // [4] all scB reads done
    if (wave < 8) {
#pragma unroll
        for (int dt = 0; dt < 4; ++dt)
#pragma unroll
            for (int r = 0; r < 4; ++r)
                osum[wave][quad * 4 + r][dt * 16 + col] = od[dt][r];
    }
    __syncthreads();                                       // [5]
    if (wave >= 8) {
#pragma unroll
        for (int dt = 0; dt < 4; ++dt)
#pragma unroll
            for (int r = 0; r < 4; ++r)
                osum[wave - 8][quad * 4 + r][dt * 16 + col] += od[dt][r];
    }
    __syncthreads();                                       // [6]

    // ---- final: 1024 threads cover 16x64 (q,d); normalize, emit hi/lo planes ----
    {
        int q = tid >> 6, d = tid & 63;
        float s = 0.f;
#pragma unroll
        for (int w = 0; w < 8; ++w) s += osum[w][q][d];
        s *= linv[q];
        size_t idx = ((size_t)b * S_ + q0 + q) * D_ + h * HD_ + d;
        unsigned short hh = f2bf(s);
        AOhi[idx] = hh;
        AOlo[idx] = f2bf(s - bf2f(hh));
    }
}

extern "C" void kernel_launch(void* const* d_in, const int* in_sizes, int n_in,
                              void* d_out, int out_size, void* d_ws, size_t ws_size,
                              hipStream_t stream) {
    const float* x  = (const float*)d_in[0];
    const float* Wq = (const float*)d_in[1];
    const float* bq = (const float*)d_in[2];
    const float* Wk = (const float*)d_in[3];
    const float* bk = (const float*)d_in[4];
    const float* Wv = (const float*)d_in[5];
    const float* bv = (const float*)d_in[6];
    const float* Wo = (const float*)d_in[7];
    const float* bo = (const float*)d_in[8];
    float* out = (float*)d_out;

    const size_t NP = (size_t)M_ * D_;      // 3,145,728 elems
    const size_t NW = (size_t)D_ * D_;      // 589,824 elems
    unsigned short* p = (unsigned short*)d_ws;
    unsigned short* xhi = p;  p += NP;
    unsigned short* xlo = p;  p += NP;
    unsigned short* Wqh = p;  p += NW;  unsigned short* Wql = p;  p += NW;
    unsigned short* Wkh = p;  p += NW;  unsigned short* Wkl = p;  p += NW;
    unsigned short* Wvh = p;  p += NW;  unsigned short* Wvl = p;  p += NW;
    unsigned short* Woh = p;  p += NW;  unsigned short* Wol = p;  p += NW;
    unsigned short* Qh  = p;  p += NP;  unsigned short* Ql  = p;  p += NP;
    unsigned short* Kh  = p;  p += NP;  unsigned short* Kl  = p;  p += NP;  // Kl unused
    unsigned short* Vth = p;  p += NP;  unsigned short* Vtl = p;  p += NP;  // Vtl unused
    // AO planes alias x planes (x dead after the V projection)
    unsigned short* AOh = xhi;
    unsigned short* AOl = xlo;

    split_kernel<<<(int)((NP + 255) / 256), 256, 0, stream>>>(x,  xhi, xlo, (int)NP);
    split_kernel<<<(int)((NW + 255) / 256), 256, 0, stream>>>(Wq, Wqh, Wql, (int)NW);
    split_kernel<<<(int)((NW + 255) / 256), 256, 0, stream>>>(Wk, Wkh, Wkl, (int)NW);
    split_kernel<<<(int)((NW + 255) / 256), 256, 0, stream>>>(Wv, Wvh, Wvl, (int)NW);
    split_kernel<<<(int)((NW + 255) / 256), 256, 0, stream>>>(Wo, Woh, Wol, (int)NW);

    dim3 g(M_ / 128, D_ / 64);              // (32, 12)
    gemm_bf16s<1, 1><<<g, 256, 0, stream>>>(xhi, xlo, Wqh, Wql, bq, nullptr, Qh, Ql);
    gemm_bf16s<1, 0><<<g, 256, 0, stream>>>(xhi, xlo, Wkh, Wkl, bk, nullptr, Kh, Kl);
    gemm_bf16s<2, 0><<<g, 256, 0, stream>>>(xhi, xlo, Wvh, Wvl, bv, nullptr, Vth, Vtl);

    attn_kernel<<<(S_ / 16) * B_ * H_, 1024, 0, stream>>>(Qh, Ql, Kh, Vth, AOh, AOl);

    gemm_bf16s<0, 0><<<g, 256, 0, stream>>>(AOh, AOl, Woh, Wol, bo, out, nullptr, nullptr);
}

// Round 6
// 469.616 us; speedup vs baseline: 8.9014x; 1.1622x over previous
//
#include <hip/hip_runtime.h>
#include <math.h>

#define B_ 2
#define S_ 2048
#define D_ 768
#define H_ 12
#define HD_ 64
#define KKEEP 614            // max(1, int(0.3*2048))
#define M_ (B_*S_)           // 4096
#define KD_ 768
#define SRW 2072             // scB row stride in ushorts (4144B rows, 16B aligned)

typedef __attribute__((ext_vector_type(8))) short bf8;   // 8 bf16 = 4 VGPR (MFMA A/B frag)
typedef __attribute__((ext_vector_type(4))) float f4;    // MFMA 16x16 C/D frag

__device__ __forceinline__ unsigned short f2bf(float f) {   // RNE fp32->bf16
    unsigned u = __float_as_uint(f);
    u += 0x7FFF + ((u >> 16) & 1);
    return (unsigned short)(u >> 16);
}
__device__ __forceinline__ float bf2f(unsigned short h) {
    return __uint_as_float((unsigned)h << 16);
}
__device__ __forceinline__ unsigned ord16(unsigned short h) {   // bf16 -> orderable u16
    return (h & 0x8000u) ? ((~(unsigned)h) & 0xFFFFu) : ((unsigned)h | 0x8000u);
}
__device__ __forceinline__ unsigned short inv16(unsigned o) {   // orderable u16 -> bf16
    return (unsigned short)((o & 0x8000u) ? (o & 0x7FFFu) : ((~o) & 0xFFFFu));
}

// fp32 -> (bf16 hi, bf16 lo) planes; a = hi + lo to ~16 mantissa bits
__global__ void split_kernel(const float* __restrict__ src,
                             unsigned short* __restrict__ hi,
                             unsigned short* __restrict__ lo, int n) {
    int i = blockIdx.x * blockDim.x + threadIdx.x;
    int stride = gridDim.x * blockDim.x;
    for (; i < n; i += stride) {
        float f = src[i];
        unsigned short h = f2bf(f);
        hi[i] = h;
        lo[i] = f2bf(f - bf2f(h));
    }
}

// C[m][n] = sum_k A[m][k]*W[n][k] + bias[n], split-bf16 (3 MFMA per product).
// MODE 0: fp32 out[m*768+n]
// MODE 1: bf16 planes, BHSD  [b][h][s][d]   (Q, K)
// MODE 2: bf16 planes, BHDS  [b][h][d][s]   (V transposed)
// WLO: also write the lo plane (needed only for Q and AO)
template<int MODE, int WLO>
__global__ __launch_bounds__(256)
void gemm_bf16s(const unsigned short* __restrict__ Ahi, const unsigned short* __restrict__ Alo,
                const unsigned short* __restrict__ Whi, const unsigned short* __restrict__ Wlo,
                const float* __restrict__ bias,
                float* __restrict__ outf,
                unsigned short* __restrict__ ohi, unsigned short* __restrict__ olo) {
    __shared__ unsigned short Ah[128][32], Al[128][32], Bh[64][32], Bl[64][32];  // 24KB
    const int bm = blockIdx.x * 128, bn = blockIdx.y * 64;
    const int tid = threadIdx.x, lane = tid & 63, wave = tid >> 6;
    const int col = lane & 15, quad = lane >> 4;

    f4 acc[2][4];
#pragma unroll
    for (int mi = 0; mi < 2; ++mi)
#pragma unroll
        for (int ni = 0; ni < 4; ++ni) { f4 z = {0.f,0.f,0.f,0.f}; acc[mi][ni] = z; }

    for (int kt = 0; kt < KD_; kt += 32) {
        __syncthreads();
#pragma unroll
        for (int c = 0; c < 2; ++c) {
            int idx = c * 256 + tid;
            int row = idx >> 2, ko = (idx & 3) * 8;
            *(uint4*)&Ah[row][ko] = *(const uint4*)&Ahi[(size_t)(bm + row) * KD_ + kt + ko];
            *(uint4*)&Al[row][ko] = *(const uint4*)&Alo[(size_t)(bm + row) * KD_ + kt + ko];
        }
        {
            int row = tid >> 2, ko = (tid & 3) * 8;
            *(uint4*)&Bh[row][ko] = *(const uint4*)&Whi[(size_t)(bn + row) * KD_ + kt + ko];
            *(uint4*)&Bl[row][ko] = *(const uint4*)&Wlo[(size_t)(bn + row) * KD_ + kt + ko];
        }
        __syncthreads();

        bf8 af[2][2], wf[4][2];
#pragma unroll
        for (int mi = 0; mi < 2; ++mi) {
            int r = wave * 32 + mi * 16 + col;
            af[mi][0] = *(const bf8*)&Ah[r][quad * 8];
            af[mi][1] = *(const bf8*)&Al[r][quad * 8];
        }
#pragma unroll
        for (int ni = 0; ni < 4; ++ni) {
            int r = ni * 16 + col;
            wf[ni][0] = *(const bf8*)&Bh[r][quad * 8];
            wf[ni][1] = *(const bf8*)&Bl[r][quad * 8];
        }
#pragma unroll
        for (int mi = 0; mi < 2; ++mi)
#pragma unroll
            for (int ni = 0; ni < 4; ++ni) {
                acc[mi][ni] = __builtin_amdgcn_mfma_f32_16x16x32_bf16(af[mi][0], wf[ni][0], acc[mi][ni], 0, 0, 0);
                acc[mi][ni] = __builtin_amdgcn_mfma_f32_16x16x32_bf16(af[mi][1], wf[ni][0], acc[mi][ni], 0, 0, 0);
                acc[mi][ni] = __builtin_amdgcn_mfma_f32_16x16x32_bf16(af[mi][0], wf[ni][1], acc[mi][ni], 0, 0, 0);
            }
    }

    float bv[4];
#pragma unroll
    for (int ni = 0; ni < 4; ++ni) bv[ni] = bias[bn + ni * 16 + col];
#pragma unroll
    for (int mi = 0; mi < 2; ++mi)
#pragma unroll
        for (int ni = 0; ni < 4; ++ni)
#pragma unroll
            for (int r = 0; r < 4; ++r) {
                int m = bm + wave * 32 + mi * 16 + quad * 4 + r;  // C row = quad*4+reg
                int n = bn + ni * 16 + col;                       // C col = lane&15
                float v = acc[mi][ni][r] + bv[ni];
                if (MODE == 0) {
                    outf[(size_t)m * D_ + n] = v;
                } else {
                    int b = m >> 11, s = m & 2047, h = n >> 6, d = n & 63;
                    size_t idx = (MODE == 1)
                        ? ((((size_t)b * H_ + h) * S_ + s) * HD_ + d)
                        : ((((size_t)b * H_ + h) * HD_ + d) * S_ + s);
                    unsigned short hh = f2bf(v);
                    ohi[idx] = hh;
                    if (WLO) olo[idx] = f2bf(v - bf2f(hh));
                }
            }
}

// Attention: block = 16 q rows of one (b,h); 1024 thr = 16 waves; wave owns 128 keys.
// QK (4-MFMA split-bf16) writes orderable-u16 scores DIRECTLY to the LDS transpose
// buffer (no persistent score registers). Wave w then owns row w in kv[16]: row max,
// 16-iter binary-search threshold, exp weights, bf16 write-back -- all wave-local,
// no atomics, no cross-wave state. PV MFMA reads P A-frags from LDS via b128.
// Register diet keeps peak ~44 VGPR -> 2 blocks/CU at launch_bounds(1024,8), no spill.
__global__ __launch_bounds__(1024, 8)
void attn_kernel(const unsigned short* __restrict__ Qhi, const unsigned short* __restrict__ Qlo,
                 const unsigned short* __restrict__ Khi,
                 const unsigned short* __restrict__ Vthi,
                 unsigned short* __restrict__ AOhi, unsigned short* __restrict__ AOlo) {
    const int bid = blockIdx.x;            // 3072 = 24 bh * 128 q-tiles
    const int xcd = bid & 7, sub = (bid >> 3) % 3, tile = bid / 24;
    const int bh = xcd * 3 + sub;          // L2 locality: 3 (b,h) per XCD
    const int b = bh / H_, h = bh % H_;
    const int q0 = tile * 16;
    const int tid = threadIdx.x, lane = tid & 63, wave = tid >> 6;   // wave 0..15
    const int col = lane & 15, quad = lane >> 4;

    __shared__ __align__(16) unsigned char arena[16 * 4144];   // 66.3KB: scB / osum alias
    unsigned short* scB = (unsigned short*)arena;              // [16][SRW] u16
    float (*osum)[16][64] = (float (*)[16][64])arena;          // [8][16][64] f32 (32KB)
    __shared__ float linv[16];

    // Q A-frags direct from global: m = col = q-local, k = quad*8+j
    const size_t qbase = ((size_t)bh * S_ + q0 + col) * HD_;
    bf8 qh0 = *(const bf8*)&Qhi[qbase + quad * 8];
    bf8 qh1 = *(const bf8*)&Qhi[qbase + 32 + quad * 8];
    bf8 ql0 = *(const bf8*)&Qlo[qbase + quad * 8];
    bf8 ql1 = *(const bf8*)&Qlo[qbase + 32 + quad * 8];

    // ---- QK^T (4-MFMA split): q = quad*4+r, key = wave*128 + t*16 + col ----
    // Scores go straight to LDS as orderable u16 (no persistent registers).
    const size_t kbb = (size_t)bh * S_ * HD_;
#pragma unroll
    for (int t = 0; t < 8; ++t) {
        const size_t kr = kbb + (size_t)(wave * 128 + t * 16 + col) * HD_;
        bf8 kh0 = *(const bf8*)&Khi[kr + quad * 8];
        bf8 kh1 = *(const bf8*)&Khi[kr + 32 + quad * 8];
        f4 a = {0.f, 0.f, 0.f, 0.f};
        a = __builtin_amdgcn_mfma_f32_16x16x32_bf16(qh0, kh0, a, 0, 0, 0);
        a = __builtin_amdgcn_mfma_f32_16x16x32_bf16(qh1, kh1, a, 0, 0, 0);
        a = __builtin_amdgcn_mfma_f32_16x16x32_bf16(ql0, kh0, a, 0, 0, 0);
        a = __builtin_amdgcn_mfma_f32_16x16x32_bf16(ql1, kh1, a, 0, 0, 0);
#pragma unroll
        for (int r = 0; r < 4; ++r)
            scB[(quad * 4 + r) * SRW + wave * 128 + t * 16 + col] =
                (unsigned short)ord16(f2bf(a[r] * 0.125f));
    }
    __syncthreads();                                       // [1] transpose visible

    // ---- wave w owns row w entirely: kv[16] dwords = 32 packed u16 keys ----
    unsigned* rowp = (unsigned*)(arena + wave * 4144);
    unsigned kv[16];
#pragma unroll
    for (int j = 0; j < 16; ++j) kv[j] = rowp[lane + 64 * j];   // conflict-free

    // row max (orderable space)
    unsigned mo = 0;
#pragma unroll
    for (int j = 0; j < 16; ++j) {
        unsigned hi = kv[j] >> 16, lo = kv[j] & 0xFFFFu;
        mo = mo > hi ? mo : hi;
        mo = mo > lo ? mo : lo;
    }
#pragma unroll
    for (int off = 1; off < 64; off <<= 1) {
        unsigned v = __shfl_xor((int)mo, off, 64);
        mo = mo > v ? mo : v;
    }
    // binary search: largest T with count(>=T) >= KKEEP  (T = 614th largest, bf16 grid)
    unsigned T = 0;
#pragma unroll
    for (int bit = 15; bit >= 0; --bit) {
        unsigned cand = T | (1u << bit);
        int cnt = 0;
#pragma unroll
        for (int j = 0; j < 16; ++j)
            cnt += (int)((kv[j] >> 16) >= cand) + (int)((kv[j] & 0xFFFFu) >= cand);
#pragma unroll
        for (int off = 1; off < 64; off <<= 1) cnt += __shfl_xor(cnt, off, 64);
        if (cnt >= KKEEP) T = cand;
    }
    const float m = bf2f(inv16(mo));

    // ---- weights from kv: w = exp(s-m) if key >= T else 0; bf16 write-back ----
    float ls = 0.f;
#pragma unroll
    for (int j = 0; j < 16; ++j) {
        unsigned v = kv[j];
        unsigned lo = v & 0xFFFFu, hi = v >> 16;
        float wl = (lo >= T) ? __expf(bf2f(inv16(lo)) - m) : 0.f;
        float wh = (hi >= T) ? __expf(bf2f(inv16(hi)) - m) : 0.f;
        ls += wl + wh;
        rowp[lane + 64 * j] = (unsigned)f2bf(wl) | ((unsigned)f2bf(wh) << 16);
    }
#pragma unroll
    for (int off = 1; off < 64; off <<= 1) ls += __shfl_xor(ls, off, 64);
    if (lane == 0) linv[wave] = 1.f / ls;
    __syncthreads();                                       // [2] weights + linv visible

    // ---- PV: A-frags (P) from scB via b128; B-frags (V^T) from global ----
    f4 od[4];
#pragma unroll
    for (int dt = 0; dt < 4; ++dt) { f4 z = {0.f,0.f,0.f,0.f}; od[dt] = z; }
    const size_t vbb = (size_t)bh * HD_ * S_;
#pragma unroll
    for (int c = 0; c < 4; ++c) {
        bf8 ph = *(const bf8*)&scB[col * SRW + wave * 128 + c * 32 + quad * 8];
        const size_t sbase = (size_t)(wave * 128 + c * 32 + quad * 8);
#pragma unroll
        for (int dt = 0; dt < 4; ++dt) {
            bf8 vh = *(const bf8*)&Vthi[vbb + (size_t)(dt * 16 + col) * S_ + sbase];
            od[dt] = __builtin_amdgcn_mfma_f32_16x16x32_bf16(ph, vh, od[dt], 0, 0, 0);
        }
    }
    __syncthreads();                                       // [3] all scB reads done
    if (wave < 8) {
#pragma unroll
        for (int dt = 0; dt < 4; ++dt)
#pragma unroll
            for (int r = 0; r < 4; ++r)
                osum[wave][quad * 4 + r][dt * 16 + col] = od[dt][r];
    }
    __syncthreads();                                       // [4]
    if (wave >= 8) {
#pragma unroll
        for (int dt = 0; dt < 4; ++dt)
#pragma unroll
            for (int r = 0; r < 4; ++r)
                osum[wave - 8][quad * 4 + r][dt * 16 + col] += od[dt][r];
    }
    __syncthreads();                                       // [5]

    // ---- final: 1024 threads cover 16x64 (q,d); normalize, emit hi/lo planes ----
    {
        int q = tid >> 6, d = tid & 63;
        float s = 0.f;
#pragma unroll
        for (int w = 0; w < 8; ++w) s += osum[w][q][d];
        s *= linv[q];
        size_t idx = ((size_t)b * S_ + q0 + q) * D_ + h * HD_ + d;
        unsigned short hh = f2bf(s);
        AOhi[idx] = hh;
        AOlo[idx] = f2bf(s - bf2f(hh));
    }
}

extern "C" void kernel_launch(void* const* d_in, const int* in_sizes, int n_in,
                              void* d_out, int out_size, void* d_ws, size_t ws_size,
                              hipStream_t stream) {
    const float* x  = (const float*)d_in[0];
    const float* Wq = (const float*)d_in[1];
    const float* bq = (const float*)d_in[2];
    const float* Wk = (const float*)d_in[3];
    const float* bk = (const float*)d_in[4];
    const float* Wv = (const float*)d_in[5];
    const float* bv = (const float*)d_in[6];
    const float* Wo = (const float*)d_in[7];
    const float* bo = (const float*)d_in[8];
    float* out = (float*)d_out;

    const size_t NP = (size_t)M_ * D_;      // 3,145,728 elems
    const size_t NW = (size_t)D_ * D_;      // 589,824 elems
    unsigned short* p = (unsigned short*)d_ws;
    unsigned short* xhi = p;  p += NP;
    unsigned short* xlo = p;  p += NP;
    unsigned short* Wqh = p;  p += NW;  unsigned short* Wql = p;  p += NW;
    unsigned short* Wkh = p;  p += NW;  unsigned short* Wkl = p;  p += NW;
    unsigned short* Wvh = p;  p += NW;  unsigned short* Wvl = p;  p += NW;
    unsigned short* Woh = p;  p += NW;  unsigned short* Wol = p;  p += NW;
    unsigned short* Qh  = p;  p += NP;  unsigned short* Ql  = p;  p += NP;
    unsigned short* Kh  = p;  p += NP;  unsigned short* Kl  = p;  p += NP;  // Kl unused
    unsigned short* Vth = p;  p += NP;  unsigned short* Vtl = p;  p += NP;  // Vtl unused
    // AO planes alias x planes (x dead after the V projection)
    unsigned short* AOh = xhi;
    unsigned short* AOl = xlo;

    split_kernel<<<(int)((NP + 255) / 256), 256, 0, stream>>>(x,  xhi, xlo, (int)NP);
    split_kernel<<<(int)((NW + 255) / 256), 256, 0, stream>>>(Wq, Wqh, Wql, (int)NW);
    split_kernel<<<(int)((NW + 255) / 256), 256, 0, stream>>>(Wk, Wkh, Wkl, (int)NW);
    split_kernel<<<(int)((NW + 255) / 256), 256, 0, stream>>>(Wv, Wvh, Wvl, (int)NW);
    split_kernel<<<(int)((NW + 255) / 256), 256, 0, stream>>>(Wo, Woh, Wol, (int)NW);

    dim3 g(M_ / 128, D_ / 64);              // (32, 12)
    gemm_bf16s<1, 1><<<g, 256, 0, stream>>>(xhi, xlo, Wqh, Wql, bq, nullptr, Qh, Ql);
    gemm_bf16s<1, 0><<<g, 256, 0, stream>>>(xhi, xlo, Wkh, Wkl, bk, nullptr, Kh, Kl);
    gemm_bf16s<2, 0><<<g, 256, 0, stream>>>(xhi, xlo, Wvh, Wvl, bv, nullptr, Vth, Vtl);

    attn_kernel<<<(S_ / 16) * B_ * H_, 1024, 0, stream>>>(Qh, Ql, Kh, Vth, AOh, AOl);

    gemm_bf16s<0, 0><<<g, 256, 0, stream>>>(AOh, AOl, Woh, Wol, bo, out, nullptr, nullptr);
}

// Round 7
// 439.904 us; speedup vs baseline: 9.5026x; 1.0675x over previous
//
#include <hip/hip_runtime.h>
#include <math.h>

#define B_ 2
#define S_ 2048
#define D_ 768
#define H_ 12
#define HD_ 64
#define KKEEP 614            // max(1, int(0.3*2048))
#define M_ (B_*S_)           // 4096
#define KD_ 768
#define SRW 2072             // scB row stride in ushorts (4144B rows, 16B aligned)

typedef __attribute__((ext_vector_type(8))) short bf8;   // 8 bf16 = 4 VGPR (MFMA A/B frag)
typedef __attribute__((ext_vector_type(4))) float f4;    // MFMA 16x16 C/D frag

__device__ __forceinline__ unsigned short f2bf(float f) {   // RNE fp32->bf16
    unsigned u = __float_as_uint(f);
    u += 0x7FFF + ((u >> 16) & 1);
    return (unsigned short)(u >> 16);
}
__device__ __forceinline__ float bf2f(unsigned short h) {
    return __uint_as_float((unsigned)h << 16);
}
__device__ __forceinline__ unsigned ord16(unsigned short h) {   // bf16 -> orderable u16
    return (h & 0x8000u) ? ((~(unsigned)h) & 0xFFFFu) : ((unsigned)h | 0x8000u);
}
__device__ __forceinline__ unsigned short inv16(unsigned o) {   // orderable u16 -> bf16
    return (unsigned short)((o & 0x8000u) ? (o & 0x7FFFu) : ((~o) & 0xFFFFu));
}

// fp32 -> (bf16 hi, bf16 lo) planes
__global__ void split_kernel(const float* __restrict__ src,
                             unsigned short* __restrict__ hi,
                             unsigned short* __restrict__ lo, int n) {
    int i = blockIdx.x * blockDim.x + threadIdx.x;
    if (i >= n) return;
    float f = src[i];
    unsigned short h = f2bf(f);
    hi[i] = h;
    lo[i] = f2bf(f - bf2f(h));
}

// 4 weight matrices -> concatenated hi/lo planes [4][768*768]; y selects source
__global__ void split_w_kernel(const float* __restrict__ w0, const float* __restrict__ w1,
                               const float* __restrict__ w2, const float* __restrict__ w3,
                               unsigned short* __restrict__ hi,
                               unsigned short* __restrict__ lo) {
    const int which = blockIdx.y;
    const float* src = which == 0 ? w0 : (which == 1 ? w1 : (which == 2 ? w2 : w3));
    int i = blockIdx.x * blockDim.x + threadIdx.x;          // 0 .. 768*768-1
    size_t o = (size_t)which * (D_ * D_) + i;
    float f = src[i];
    unsigned short h = f2bf(f);
    hi[o] = h;
    lo[o] = f2bf(f - bf2f(h));
}

// Fused Q/K/V projection: C[m][n] = sum_k x[m][k]*Wcat[n][k] + bias, split-bf16
// (3 MFMA/product). Tile 128(M) x 64(N); grid.y in [0,36): which = y/12.
//   which 0 (Q): BHSD hi+lo   which 1 (K): BHSD hi   which 2 (V): BHDS hi
__global__ __launch_bounds__(256)
void gemm_qkv(const unsigned short* __restrict__ Ahi, const unsigned short* __restrict__ Alo,
              const unsigned short* __restrict__ Wch, const unsigned short* __restrict__ Wcl,
              const float* __restrict__ bq, const float* __restrict__ bk,
              const float* __restrict__ bv,
              unsigned short* __restrict__ Qh, unsigned short* __restrict__ Ql,
              unsigned short* __restrict__ Kh, unsigned short* __restrict__ Vth) {
    __shared__ unsigned short Ah[128][32], Al[128][32], Bh[64][32], Bl[64][32];  // 24KB
    const int bm = blockIdx.x * 128, bnG = blockIdx.y * 64;
    const int which = blockIdx.y / 12;                  // 0=Q 1=K 2=V
    const int bn = bnG - which * 768;                   // local col tile base
    const float* bias = which == 0 ? bq : (which == 1 ? bk : bv);
    const int tid = threadIdx.x, lane = tid & 63, wave = tid >> 6;
    const int col = lane & 15, quad = lane >> 4;

    f4 acc[2][4];
#pragma unroll
    for (int mi = 0; mi < 2; ++mi)
#pragma unroll
        for (int ni = 0; ni < 4; ++ni) { f4 z = {0.f,0.f,0.f,0.f}; acc[mi][ni] = z; }

    for (int kt = 0; kt < KD_; kt += 32) {
        __syncthreads();
#pragma unroll
        for (int c = 0; c < 2; ++c) {
            int idx = c * 256 + tid;
            int row = idx >> 2, ko = (idx & 3) * 8;
            *(uint4*)&Ah[row][ko] = *(const uint4*)&Ahi[(size_t)(bm + row) * KD_ + kt + ko];
            *(uint4*)&Al[row][ko] = *(const uint4*)&Alo[(size_t)(bm + row) * KD_ + kt + ko];
        }
        {
            int row = tid >> 2, ko = (tid & 3) * 8;
            *(uint4*)&Bh[row][ko] = *(const uint4*)&Wch[(size_t)(bnG + row) * KD_ + kt + ko];
            *(uint4*)&Bl[row][ko] = *(const uint4*)&Wcl[(size_t)(bnG + row) * KD_ + kt + ko];
        }
        __syncthreads();

        bf8 af[2][2], wf[4][2];
#pragma unroll
        for (int mi = 0; mi < 2; ++mi) {
            int r = wave * 32 + mi * 16 + col;
            af[mi][0] = *(const bf8*)&Ah[r][quad * 8];
            af[mi][1] = *(const bf8*)&Al[r][quad * 8];
        }
#pragma unroll
        for (int ni = 0; ni < 4; ++ni) {
            int r = ni * 16 + col;
            wf[ni][0] = *(const bf8*)&Bh[r][quad * 8];
            wf[ni][1] = *(const bf8*)&Bl[r][quad * 8];
        }
#pragma unroll
        for (int mi = 0; mi < 2; ++mi)
#pragma unroll
            for (int ni = 0; ni < 4; ++ni) {
                acc[mi][ni] = __builtin_amdgcn_mfma_f32_16x16x32_bf16(af[mi][0], wf[ni][0], acc[mi][ni], 0, 0, 0);
                acc[mi][ni] = __builtin_amdgcn_mfma_f32_16x16x32_bf16(af[mi][1], wf[ni][0], acc[mi][ni], 0, 0, 0);
                acc[mi][ni] = __builtin_amdgcn_mfma_f32_16x16x32_bf16(af[mi][0], wf[ni][1], acc[mi][ni], 0, 0, 0);
            }
    }

    float bvv[4];
#pragma unroll
    for (int ni = 0; ni < 4; ++ni) bvv[ni] = bias[bn + ni * 16 + col];
#pragma unroll
    for (int mi = 0; mi < 2; ++mi)
#pragma unroll
        for (int ni = 0; ni < 4; ++ni)
#pragma unroll
            for (int r = 0; r < 4; ++r) {
                int m = bm + wave * 32 + mi * 16 + quad * 4 + r;  // C row = quad*4+reg
                int n = bn + ni * 16 + col;                       // C col = lane&15
                float v = acc[mi][ni][r] + bvv[ni];
                int b = m >> 11, s = m & 2047, h = n >> 6, d = n & 63;
                unsigned short hh = f2bf(v);
                if (which == 0) {
                    size_t idx = (((size_t)b * H_ + h) * S_ + s) * HD_ + d;
                    Qh[idx] = hh;
                    Ql[idx] = f2bf(v - bf2f(hh));
                } else if (which == 1) {
                    Kh[(((size_t)b * H_ + h) * S_ + s) * HD_ + d] = hh;
                } else {
                    Vth[(((size_t)b * H_ + h) * HD_ + d) * S_ + s] = hh;
                }
            }
}

// O-projection: fp32 out = AO @ Wo^T + bo (split-bf16, 3 MFMA)
__global__ __launch_bounds__(256)
void gemm_o(const unsigned short* __restrict__ Ahi, const unsigned short* __restrict__ Alo,
            const unsigned short* __restrict__ Whi, const unsigned short* __restrict__ Wlo,
            const float* __restrict__ bias, float* __restrict__ outf) {
    __shared__ unsigned short Ah[128][32], Al[128][32], Bh[64][32], Bl[64][32];
    const int bm = blockIdx.x * 128, bn = blockIdx.y * 64;
    const int tid = threadIdx.x, lane = tid & 63, wave = tid >> 6;
    const int col = lane & 15, quad = lane >> 4;

    f4 acc[2][4];
#pragma unroll
    for (int mi = 0; mi < 2; ++mi)
#pragma unroll
        for (int ni = 0; ni < 4; ++ni) { f4 z = {0.f,0.f,0.f,0.f}; acc[mi][ni] = z; }

    for (int kt = 0; kt < KD_; kt += 32) {
        __syncthreads();
#pragma unroll
        for (int c = 0; c < 2; ++c) {
            int idx = c * 256 + tid;
            int row = idx >> 2, ko = (idx & 3) * 8;
            *(uint4*)&Ah[row][ko] = *(const uint4*)&Ahi[(size_t)(bm + row) * KD_ + kt + ko];
            *(uint4*)&Al[row][ko] = *(const uint4*)&Alo[(size_t)(bm + row) * KD_ + kt + ko];
        }
        {
            int row = tid >> 2, ko = (tid & 3) * 8;
            *(uint4*)&Bh[row][ko] = *(const uint4*)&Whi[(size_t)(bn + row) * KD_ + kt + ko];
            *(uint4*)&Bl[row][ko] = *(const uint4*)&Wlo[(size_t)(bn + row) * KD_ + kt + ko];
        }
        __syncthreads();

        bf8 af[2][2], wf[4][2];
#pragma unroll
        for (int mi = 0; mi < 2; ++mi) {
            int r = wave * 32 + mi * 16 + col;
            af[mi][0] = *(const bf8*)&Ah[r][quad * 8];
            af[mi][1] = *(const bf8*)&Al[r][quad * 8];
        }
#pragma unroll
        for (int ni = 0; ni < 4; ++ni) {
            int r = ni * 16 + col;
            wf[ni][0] = *(const bf8*)&Bh[r][quad * 8];
            wf[ni][1] = *(const bf8*)&Bl[r][quad * 8];
        }
#pragma unroll
        for (int mi = 0; mi < 2; ++mi)
#pragma unroll
            for (int ni = 0; ni < 4; ++ni) {
                acc[mi][ni] = __builtin_amdgcn_mfma_f32_16x16x32_bf16(af[mi][0], wf[ni][0], acc[mi][ni], 0, 0, 0);
                acc[mi][ni] = __builtin_amdgcn_mfma_f32_16x16x32_bf16(af[mi][1], wf[ni][0], acc[mi][ni], 0, 0, 0);
                acc[mi][ni] = __builtin_amdgcn_mfma_f32_16x16x32_bf16(af[mi][0], wf[ni][1], acc[mi][ni], 0, 0, 0);
            }
    }

    float bvv[4];
#pragma unroll
    for (int ni = 0; ni < 4; ++ni) bvv[ni] = bias[bn + ni * 16 + col];
#pragma unroll
    for (int mi = 0; mi < 2; ++mi)
#pragma unroll
        for (int ni = 0; ni < 4; ++ni)
#pragma unroll
            for (int r = 0; r < 4; ++r) {
                int m = bm + wave * 32 + mi * 16 + quad * 4 + r;
                int n = bn + ni * 16 + col;
                outf[(size_t)m * D_ + n] = acc[mi][ni][r] + bvv[ni];
            }
}

// Attention: block = 16 q rows of one (b,h); 1024 thr = 16 waves; wave owns 128 keys.
// QK (4-MFMA split-bf16) writes orderable-u16 scores directly to LDS. Wave w owns row
// w in kv[16]: max, 16-iter binary-search threshold, exp weights, bf16 write-back --
// all wave-local, no atomics. PV MFMA reads P A-frags from LDS via b128.
// #pragma unroll 1 on the QK/PV loops keeps in-flight fragments to one iteration so
// the allocator fits the 64-reg cap of (1024,8) without scratch spill.
__global__ __launch_bounds__(1024, 8)
void attn_kernel(const unsigned short* __restrict__ Qhi, const unsigned short* __restrict__ Qlo,
                 const unsigned short* __restrict__ Khi,
                 const unsigned short* __restrict__ Vthi,
                 unsigned short* __restrict__ AOhi, unsigned short* __restrict__ AOlo) {
    const int bid = blockIdx.x;            // 3072 = 24 bh * 128 q-tiles
    const int xcd = bid & 7, sub = (bid >> 3) % 3, tile = bid / 24;
    const int bh = xcd * 3 + sub;          // L2 locality: 3 (b,h) per XCD
    const int b = bh / H_, h = bh % H_;
    const int q0 = tile * 16;
    const int tid = threadIdx.x, lane = tid & 63, wave = tid >> 6;   // wave 0..15
    const int col = lane & 15, quad = lane >> 4;

    __shared__ __align__(16) unsigned char arena[16 * 4144];   // 66.3KB: scB / osum alias
    unsigned short* scB = (unsigned short*)arena;              // [16][SRW] u16
    float (*osum)[16][64] = (float (*)[16][64])arena;          // [8][16][64] f32 (32KB)
    __shared__ float linv[16];

    // Q A-frags direct from global: m = col = q-local, k = quad*8+j
    const size_t qbase = ((size_t)bh * S_ + q0 + col) * HD_;
    bf8 qh0 = *(const bf8*)&Qhi[qbase + quad * 8];
    bf8 qh1 = *(const bf8*)&Qhi[qbase + 32 + quad * 8];
    bf8 ql0 = *(const bf8*)&Qlo[qbase + quad * 8];
    bf8 ql1 = *(const bf8*)&Qlo[qbase + 32 + quad * 8];

    // ---- QK^T (4-MFMA split): q = quad*4+r, key = wave*128 + t*16 + col ----
    const size_t kbb = (size_t)bh * S_ * HD_;
#pragma unroll 1
    for (int t = 0; t < 8; ++t) {
        const size_t kr = kbb + (size_t)(wave * 128 + t * 16 + col) * HD_;
        bf8 kh0 = *(const bf8*)&Khi[kr + quad * 8];
        bf8 kh1 = *(const bf8*)&Khi[kr + 32 + quad * 8];
        f4 a = {0.f, 0.f, 0.f, 0.f};
        a = __builtin_amdgcn_mfma_f32_16x16x32_bf16(qh0, kh0, a, 0, 0, 0);
        a = __builtin_amdgcn_mfma_f32_16x16x32_bf16(qh1, kh1, a, 0, 0, 0);
        a = __builtin_amdgcn_mfma_f32_16x16x32_bf16(ql0, kh0, a, 0, 0, 0);
        a = __builtin_amdgcn_mfma_f32_16x16x32_bf16(ql1, kh1, a, 0, 0, 0);
#pragma unroll
        for (int r = 0; r < 4; ++r)
            scB[(quad * 4 + r) * SRW + wave * 128 + t * 16 + col] =
                (unsigned short)ord16(f2bf(a[r] * 0.125f));
    }
    __syncthreads();                                       // [1] transpose visible

    // ---- wave w owns row w entirely: kv[16] dwords = 32 packed u16 keys ----
    unsigned* rowp = (unsigned*)(arena + wave * 4144);
    unsigned kv[16];
#pragma unroll
    for (int j = 0; j < 16; ++j) kv[j] = rowp[lane + 64 * j];   // conflict-free

    // row max (orderable space)
    unsigned mo = 0;
#pragma unroll
    for (int j = 0; j < 16; ++j) {
        unsigned hi = kv[j] >> 16, lo = kv[j] & 0xFFFFu;
        mo = mo > hi ? mo : hi;
        mo = mo > lo ? mo : lo;
    }
#pragma unroll
    for (int off = 1; off < 64; off <<= 1) {
        unsigned v = __shfl_xor((int)mo, off, 64);
        mo = mo > v ? mo : v;
    }
    // binary search: largest T with count(>=T) >= KKEEP  (T = 614th largest, bf16 grid)
    unsigned T = 0;
#pragma unroll 1
    for (int bit = 15; bit >= 0; --bit) {
        unsigned cand = T | (1u << bit);
        int cnt = 0;
#pragma unroll
        for (int j = 0; j < 16; ++j)
            cnt += (int)((kv[j] >> 16) >= cand) + (int)((kv[j] & 0xFFFFu) >= cand);
#pragma unroll
        for (int off = 1; off < 64; off <<= 1) cnt += __shfl_xor(cnt, off, 64);
        if (cnt >= KKEEP) T = cand;
    }
    const float m = bf2f(inv16(mo));

    // ---- weights from kv: w = exp(s-m) if key >= T else 0; bf16 write-back ----
    float ls = 0.f;
#pragma unroll 1
    for (int j = 0; j < 16; ++j) {
        unsigned v = kv[j];
        unsigned lo = v & 0xFFFFu, hi = v >> 16;
        float wl = (lo >= T) ? __expf(bf2f(inv16(lo)) - m) : 0.f;
        float wh = (hi >= T) ? __expf(bf2f(inv16(hi)) - m) : 0.f;
        ls += wl + wh;
        rowp[lane + 64 * j] = (unsigned)f2bf(wl) | ((unsigned)f2bf(wh) << 16);
    }
#pragma unroll
    for (int off = 1; off < 64; off <<= 1) ls += __shfl_xor(ls, off, 64);
    if (lane == 0) linv[wave] = 1.f / ls;
    __syncthreads();                                       // [2] weights + linv visible

    // ---- PV: A-frags (P) from scB via b128; B-frags (V^T) from global ----
    f4 od[4];
#pragma unroll
    for (int dt = 0; dt < 4; ++dt) { f4 z = {0.f,0.f,0.f,0.f}; od[dt] = z; }
    const size_t vbb = (size_t)bh * HD_ * S_;
#pragma unroll 1
    for (int c = 0; c < 4; ++c) {
        bf8 ph = *(const bf8*)&scB[col * SRW + wave * 128 + c * 32 + quad * 8];
        const size_t sbase = (size_t)(wave * 128 + c * 32 + quad * 8);
#pragma unroll
        for (int dt = 0; dt < 4; ++dt) {
            bf8 vh = *(const bf8*)&Vthi[vbb + (size_t)(dt * 16 + col) * S_ + sbase];
            od[dt] = __builtin_amdgcn_mfma_f32_16x16x32_bf16(ph, vh, od[dt], 0, 0, 0);
        }
    }
    __syncthreads();                                       // [3] all scB reads done
    if (wave < 8) {
#pragma unroll
        for (int dt = 0; dt < 4; ++dt)
#pragma unroll
            for (int r = 0; r < 4; ++r)
                osum[wave][quad * 4 + r][dt * 16 + col] = od[dt][r];
    }
    __syncthreads();                                       // [4]
    if (wave >= 8) {
#pragma unroll
        for (int dt = 0; dt < 4; ++dt)
#pragma unroll
            for (int r = 0; r < 4; ++r)
                osum[wave - 8][quad * 4 + r][dt * 16 + col] += od[dt][r];
    }
    __syncthreads();                                       // [5]

    // ---- final: 1024 threads cover 16x64 (q,d); normalize, emit hi/lo planes ----
    {
        int q = tid >> 6, d = tid & 63;
        float s = 0.f;
#pragma unroll
        for (int w = 0; w < 8; ++w) s += osum[w][q][d];
        s *= linv[q];
        size_t idx = ((size_t)b * S_ + q0 + q) * D_ + h * HD_ + d;
        unsigned short hh = f2bf(s);
        AOhi[idx] = hh;
        AOlo[idx] = f2bf(s - bf2f(hh));
    }
}

extern "C" void kernel_launch(void* const* d_in, const int* in_sizes, int n_in,
                              void* d_out, int out_size, void* d_ws, size_t ws_size,
                              hipStream_t stream) {
    const float* x  = (const float*)d_in[0];
    const float* Wq = (const float*)d_in[1];
    const float* bq = (const float*)d_in[2];
    const float* Wk = (const float*)d_in[3];
    const float* bk = (const float*)d_in[4];
    const float* Wv = (const float*)d_in[5];
    const float* bv = (const float*)d_in[6];
    const float* Wo = (const float*)d_in[7];
    const float* bo = (const float*)d_in[8];
    float* out = (float*)d_out;

    const size_t NP = (size_t)M_ * D_;      // 3,145,728 elems
    const size_t NW = (size_t)D_ * D_;      // 589,824 elems
    unsigned short* p = (unsigned short*)d_ws;
    unsigned short* xhi = p;  p += NP;
    unsigned short* xlo = p;  p += NP;
    unsigned short* Wch = p;  p += 4 * NW;   // concatenated [Wq|Wk|Wv|Wo] hi
    unsigned short* Wcl = p;  p += 4 * NW;   // concatenated lo
    unsigned short* Qh  = p;  p += NP;  unsigned short* Ql  = p;  p += NP;
    unsigned short* Kh  = p;  p += NP;
    unsigned short* Vth = p;  p += NP;
    // AO planes alias x planes (x dead after the projections)
    unsigned short* AOh = xhi;
    unsigned short* AOl = xlo;

    split_kernel<<<(int)(NP / 256), 256, 0, stream>>>(x, xhi, xlo, (int)NP);
    {
        dim3 gw((unsigned)(NW / 256), 4);
        split_w_kernel<<<gw, 256, 0, stream>>>(Wq, Wk, Wv, Wo, Wch, Wcl);
    }

    {
        dim3 g(M_ / 128, 36);               // 3 x 768/64 column tiles
        gemm_qkv<<<g, 256, 0, stream>>>(xhi, xlo, Wch, Wcl, bq, bk, bv,
                                        Qh, Ql, Kh, Vth);
    }

    attn_kernel<<<(S_ / 16) * B_ * H_, 1024, 0, stream>>>(Qh, Ql, Kh, Vth, AOh, AOl);

    {
        dim3 g(M_ / 128, D_ / 64);
        gemm_o<<<g, 256, 0, stream>>>(AOh, AOl, Wch + 3 * NW, Wcl + 3 * NW, bo, out);
    }
}

// Round 8
// 430.260 us; speedup vs baseline: 9.7156x; 1.0224x over previous
//
#include <hip/hip_runtime.h>
#include <math.h>

#define B_ 2
#define S_ 2048
#define D_ 768
#define H_ 12
#define HD_ 64
#define KKEEP 614            // max(1, int(0.3*2048))
#define M_ (B_*S_)           // 4096
#define KD_ 768
#define SRW 2072             // scB row stride in ushorts (4144B rows, 16B aligned)

typedef __attribute__((ext_vector_type(8))) short bf8;   // 8 bf16 = 4 VGPR (MFMA A/B frag)
typedef __attribute__((ext_vector_type(4))) float f4;    // MFMA 16x16 C/D frag

__device__ __forceinline__ unsigned short f2bf(float f) {   // RNE fp32->bf16
    unsigned u = __float_as_uint(f);
    u += 0x7FFF + ((u >> 16) & 1);
    return (unsigned short)(u >> 16);
}
__device__ __forceinline__ float bf2f(unsigned short h) {
    return __uint_as_float((unsigned)h << 16);
}
// fp32 -> orderable-u16 (bf16-RNE in orderable space; tie direction differs from
// value-space RNE only on exact half-ulp ties -- numerically irrelevant)
__device__ __forceinline__ unsigned f2ord16(float f) {
    unsigned u = __float_as_uint(f);
    unsigned o32 = u ^ ((unsigned)((int)u >> 31) | 0x80000000u);
    return (o32 + 0x7FFFu + ((o32 >> 16) & 1u)) >> 16;
}
// orderable-u16 -> fp32 (exact bf16 value)
__device__ __forceinline__ float ord16_to_f(unsigned o16) {
    unsigned o = o16 << 16;
    unsigned mask = 0x80000000u | ~(unsigned)((int)o >> 31);
    return __uint_as_float((o ^ mask) & 0xFFFF0000u);
}

// fp32 -> (bf16 hi, bf16 lo) planes
__global__ void split_kernel(const float* __restrict__ src,
                             unsigned short* __restrict__ hi,
                             unsigned short* __restrict__ lo, int n) {
    int i = blockIdx.x * blockDim.x + threadIdx.x;
    if (i >= n) return;
    float f = src[i];
    unsigned short h = f2bf(f);
    hi[i] = h;
    lo[i] = f2bf(f - bf2f(h));
}

// 4 weight matrices -> concatenated hi/lo planes [4][768*768]; y selects source
__global__ void split_w_kernel(const float* __restrict__ w0, const float* __restrict__ w1,
                               const float* __restrict__ w2, const float* __restrict__ w3,
                               unsigned short* __restrict__ hi,
                               unsigned short* __restrict__ lo) {
    const int which = blockIdx.y;
    const float* src = which == 0 ? w0 : (which == 1 ? w1 : (which == 2 ? w2 : w3));
    int i = blockIdx.x * blockDim.x + threadIdx.x;          // 0 .. 768*768-1
    size_t o = (size_t)which * (D_ * D_) + i;
    float f = src[i];
    unsigned short h = f2bf(f);
    hi[o] = h;
    lo[o] = f2bf(f - bf2f(h));
}

// Fused Q/K/V projection: C[m][n] = sum_k x[m][k]*Wcat[n][k] + bias, split-bf16
// (3 MFMA/product). Tile 128(M) x 64(N); grid.y in [0,36): which = y/12.
//   which 0 (Q): BHSD hi+lo, PRE-SCALED by 0.125 (fold softmax scale here)
//   which 1 (K): BHSD hi     which 2 (V): BHDS hi
__global__ __launch_bounds__(256)
void gemm_qkv(const unsigned short* __restrict__ Ahi, const unsigned short* __restrict__ Alo,
              const unsigned short* __restrict__ Wch, const unsigned short* __restrict__ Wcl,
              const float* __restrict__ bq, const float* __restrict__ bk,
              const float* __restrict__ bv,
              unsigned short* __restrict__ Qh, unsigned short* __restrict__ Ql,
              unsigned short* __restrict__ Kh, unsigned short* __restrict__ Vth) {
    __shared__ unsigned short Ah[128][32], Al[128][32], Bh[64][32], Bl[64][32];  // 24KB
    const int bm = blockIdx.x * 128, bnG = blockIdx.y * 64;
    const int which = blockIdx.y / 12;                  // 0=Q 1=K 2=V
    const int bn = bnG - which * 768;                   // local col tile base
    const float* bias = which == 0 ? bq : (which == 1 ? bk : bv);
    const int tid = threadIdx.x, lane = tid & 63, wave = tid >> 6;
    const int col = lane & 15, quad = lane >> 4;

    f4 acc[2][4];
#pragma unroll
    for (int mi = 0; mi < 2; ++mi)
#pragma unroll
        for (int ni = 0; ni < 4; ++ni) { f4 z = {0.f,0.f,0.f,0.f}; acc[mi][ni] = z; }

    for (int kt = 0; kt < KD_; kt += 32) {
        __syncthreads();
#pragma unroll
        for (int c = 0; c < 2; ++c) {
            int idx = c * 256 + tid;
            int row = idx >> 2, ko = (idx & 3) * 8;
            *(uint4*)&Ah[row][ko] = *(const uint4*)&Ahi[(size_t)(bm + row) * KD_ + kt + ko];
            *(uint4*)&Al[row][ko] = *(const uint4*)&Alo[(size_t)(bm + row) * KD_ + kt + ko];
        }
        {
            int row = tid >> 2, ko = (tid & 3) * 8;
            *(uint4*)&Bh[row][ko] = *(const uint4*)&Wch[(size_t)(bnG + row) * KD_ + kt + ko];
            *(uint4*)&Bl[row][ko] = *(const uint4*)&Wcl[(size_t)(bnG + row) * KD_ + kt + ko];
        }
        __syncthreads();

        bf8 af[2][2], wf[4][2];
#pragma unroll
        for (int mi = 0; mi < 2; ++mi) {
            int r = wave * 32 + mi * 16 + col;
            af[mi][0] = *(const bf8*)&Ah[r][quad * 8];
            af[mi][1] = *(const bf8*)&Al[r][quad * 8];
        }
#pragma unroll
        for (int ni = 0; ni < 4; ++ni) {
            int r = ni * 16 + col;
            wf[ni][0] = *(const bf8*)&Bh[r][quad * 8];
            wf[ni][1] = *(const bf8*)&Bl[r][quad * 8];
        }
#pragma unroll
        for (int mi = 0; mi < 2; ++mi)
#pragma unroll
            for (int ni = 0; ni < 4; ++ni) {
                acc[mi][ni] = __builtin_amdgcn_mfma_f32_16x16x32_bf16(af[mi][0], wf[ni][0], acc[mi][ni], 0, 0, 0);
                acc[mi][ni] = __builtin_amdgcn_mfma_f32_16x16x32_bf16(af[mi][1], wf[ni][0], acc[mi][ni], 0, 0, 0);
                acc[mi][ni] = __builtin_amdgcn_mfma_f32_16x16x32_bf16(af[mi][0], wf[ni][1], acc[mi][ni], 0, 0, 0);
            }
    }

    float bvv[4];
#pragma unroll
    for (int ni = 0; ni < 4; ++ni) bvv[ni] = bias[bn + ni * 16 + col];
#pragma unroll
    for (int mi = 0; mi < 2; ++mi)
#pragma unroll
        for (int ni = 0; ni < 4; ++ni)
#pragma unroll
            for (int r = 0; r < 4; ++r) {
                int m = bm + wave * 32 + mi * 16 + quad * 4 + r;  // C row = quad*4+reg
                int n = bn + ni * 16 + col;                       // C col = lane&15
                float v = acc[mi][ni][r] + bvv[ni];
                if (which == 0) v *= 0.125f;                      // fold 1/sqrt(64)
                int b = m >> 11, s = m & 2047, h = n >> 6, d = n & 63;
                unsigned short hh = f2bf(v);
                if (which == 0) {
                    size_t idx = (((size_t)b * H_ + h) * S_ + s) * HD_ + d;
                    Qh[idx] = hh;
                    Ql[idx] = f2bf(v - bf2f(hh));
                } else if (which == 1) {
                    Kh[(((size_t)b * H_ + h) * S_ + s) * HD_ + d] = hh;
                } else {
                    Vth[(((size_t)b * H_ + h) * HD_ + d) * S_ + s] = hh;
                }
            }
}

// O-projection: fp32 out = AO @ Wo^T + bo (split-bf16, 3 MFMA)
__global__ __launch_bounds__(256)
void gemm_o(const unsigned short* __restrict__ Ahi, const unsigned short* __restrict__ Alo,
            const unsigned short* __restrict__ Whi, const unsigned short* __restrict__ Wlo,
            const float* __restrict__ bias, float* __restrict__ outf) {
    __shared__ unsigned short Ah[128][32], Al[128][32], Bh[64][32], Bl[64][32];
    const int bm = blockIdx.x * 128, bn = blockIdx.y * 64;
    const int tid = threadIdx.x, lane = tid & 63, wave = tid >> 6;
    const int col = lane & 15, quad = lane >> 4;

    f4 acc[2][4];
#pragma unroll
    for (int mi = 0; mi < 2; ++mi)
#pragma unroll
        for (int ni = 0; ni < 4; ++ni) { f4 z = {0.f,0.f,0.f,0.f}; acc[mi][ni] = z; }

    for (int kt = 0; kt < KD_; kt += 32) {
        __syncthreads();
#pragma unroll
        for (int c = 0; c < 2; ++c) {
            int idx = c * 256 + tid;
            int row = idx >> 2, ko = (idx & 3) * 8;
            *(uint4*)&Ah[row][ko] = *(const uint4*)&Ahi[(size_t)(bm + row) * KD_ + kt + ko];
            *(uint4*)&Al[row][ko] = *(const uint4*)&Alo[(size_t)(bm + row) * KD_ + kt + ko];
        }
        {
            int row = tid >> 2, ko = (tid & 3) * 8;
            *(uint4*)&Bh[row][ko] = *(const uint4*)&Whi[(size_t)(bn + row) * KD_ + kt + ko];
            *(uint4*)&Bl[row][ko] = *(const uint4*)&Wlo[(size_t)(bn + row) * KD_ + kt + ko];
        }
        __syncthreads();

        bf8 af[2][2], wf[4][2];
#pragma unroll
        for (int mi = 0; mi < 2; ++mi) {
            int r = wave * 32 + mi * 16 + col;
            af[mi][0] = *(const bf8*)&Ah[r][quad * 8];
            af[mi][1] = *(const bf8*)&Al[r][quad * 8];
        }
#pragma unroll
        for (int ni = 0; ni < 4; ++ni) {
            int r = ni * 16 + col;
            wf[ni][0] = *(const bf8*)&Bh[r][quad * 8];
            wf[ni][1] = *(const bf8*)&Bl[r][quad * 8];
        }
#pragma unroll
        for (int mi = 0; mi < 2; ++mi)
#pragma unroll
            for (int ni = 0; ni < 4; ++ni) {
                acc[mi][ni] = __builtin_amdgcn_mfma_f32_16x16x32_bf16(af[mi][0], wf[ni][0], acc[mi][ni], 0, 0, 0);
                acc[mi][ni] = __builtin_amdgcn_mfma_f32_16x16x32_bf16(af[mi][1], wf[ni][0], acc[mi][ni], 0, 0, 0);
                acc[mi][ni] = __builtin_amdgcn_mfma_f32_16x16x32_bf16(af[mi][0], wf[ni][1], acc[mi][ni], 0, 0, 0);
            }
    }

    float bvv[4];
#pragma unroll
    for (int ni = 0; ni < 4; ++ni) bvv[ni] = bias[bn + ni * 16 + col];
#pragma unroll
    for (int mi = 0; mi < 2; ++mi)
#pragma unroll
        for (int ni = 0; ni < 4; ++ni)
#pragma unroll
            for (int r = 0; r < 4; ++r) {
                int m = bm + wave * 32 + mi * 16 + quad * 4 + r;
                int n = bn + ni * 16 + col;
                outf[(size_t)m * D_ + n] = acc[mi][ni][r] + bvv[ni];
            }
}

// Attention: block = 16 q rows of one (b,h); 1024 thr = 16 waves; wave owns 128 keys
// for QK, then one full row for selection. Selection count via __ballot+__popcll:
// 1 v_cmp (VALU) + s_bcnt/s_add (SALU pipe) per 64 keys, ZERO shuffle reductions.
// Packed compare trick: (hi,lo) >= (cand,0) <=> hi >= cand; (lo<<16) likewise.
__global__ __launch_bounds__(1024, 8)
void attn_kernel(const unsigned short* __restrict__ Qhi, const unsigned short* __restrict__ Qlo,
                 const unsigned short* __restrict__ Khi,
                 const unsigned short* __restrict__ Vthi,
                 unsigned short* __restrict__ AOhi, unsigned short* __restrict__ AOlo) {
    const int bid = blockIdx.x;            // 3072 = 24 bh * 128 q-tiles
    const int xcd = bid & 7, sub = (bid >> 3) % 3, tile = bid / 24;
    const int bh = xcd * 3 + sub;          // L2 locality: 3 (b,h) per XCD
    const int b = bh / H_, h = bh % H_;
    const int q0 = tile * 16;
    const int tid = threadIdx.x, lane = tid & 63, wave = tid >> 6;   // wave 0..15
    const int col = lane & 15, quad = lane >> 4;

    __shared__ __align__(16) unsigned char arena[16 * 4144];   // 66.3KB
    unsigned short* scB = (unsigned short*)arena;              // [16][SRW] u16
    float (*osum)[16][64] = (float (*)[16][64])arena;          // [16][16][64] f32 (64KB)
    __shared__ float linv[16];

    // Q A-frags direct from global: m = col = q-local, k = quad*8+j  (Q pre-scaled)
    const size_t qbase = ((size_t)bh * S_ + q0 + col) * HD_;
    bf8 qh0 = *(const bf8*)&Qhi[qbase + quad * 8];
    bf8 qh1 = *(const bf8*)&Qhi[qbase + 32 + quad * 8];
    bf8 ql0 = *(const bf8*)&Qlo[qbase + quad * 8];
    bf8 ql1 = *(const bf8*)&Qlo[qbase + 32 + quad * 8];

    // ---- QK^T (4-MFMA split): q = quad*4+r, key = wave*128 + t*16 + col ----
    const size_t kbb = (size_t)bh * S_ * HD_;
#pragma unroll 1
    for (int t = 0; t < 8; ++t) {
        const size_t kr = kbb + (size_t)(wave * 128 + t * 16 + col) * HD_;
        bf8 kh0 = *(const bf8*)&Khi[kr + quad * 8];
        bf8 kh1 = *(const bf8*)&Khi[kr + 32 + quad * 8];
        f4 a = {0.f, 0.f, 0.f, 0.f};
        a = __builtin_amdgcn_mfma_f32_16x16x32_bf16(qh0, kh0, a, 0, 0, 0);
        a = __builtin_amdgcn_mfma_f32_16x16x32_bf16(qh1, kh1, a, 0, 0, 0);
        a = __builtin_amdgcn_mfma_f32_16x16x32_bf16(ql0, kh0, a, 0, 0, 0);
        a = __builtin_amdgcn_mfma_f32_16x16x32_bf16(ql1, kh1, a, 0, 0, 0);
#pragma unroll
        for (int r = 0; r < 4; ++r)
            scB[(quad * 4 + r) * SRW + wave * 128 + t * 16 + col] =
                (unsigned short)f2ord16(a[r]);
    }
    __syncthreads();                                       // [1] transpose visible

    // ---- wave w owns row w: kv[16] packed dwords + pre-shifted kvs[16] ----
    unsigned* rowp = (unsigned*)(arena + wave * 4144);
    unsigned kv[16], kvs[16];
#pragma unroll
    for (int j = 0; j < 16; ++j) kv[j] = rowp[lane + 64 * j];   // conflict-free
#pragma unroll
    for (int j = 0; j < 16; ++j) kvs[j] = kv[j] << 16;

    // row max: u32 max's high half = max of high halves (lexicographic dominance)
    unsigned Mhi = 0, Mlo = 0;
#pragma unroll
    for (int j = 0; j < 16; ++j) {
        Mhi = kv[j]  > Mhi ? kv[j]  : Mhi;
        Mlo = kvs[j] > Mlo ? kvs[j] : Mlo;
    }
    unsigned mo = (Mhi >> 16) > (Mlo >> 16) ? (Mhi >> 16) : (Mlo >> 16);
#pragma unroll
    for (int off = 1; off < 64; off <<= 1) {
        unsigned v = __shfl_xor((int)mo, off, 64);
        mo = mo > v ? mo : v;
    }
    const float m = ord16_to_f(mo);

    // ---- threshold: largest T with count(>=T) >= KKEEP; ballot+popcount ----
    unsigned T = 0;
#pragma unroll 1
    for (int bit = 15; bit >= 0; --bit) {
        unsigned candh = (T | (1u << bit)) << 16;
        int cnt = 0;
#pragma unroll
        for (int j = 0; j < 16; ++j) {
            cnt += __popcll(__ballot(kv[j]  >= candh));    // hi halves
            cnt += __popcll(__ballot(kvs[j] >= candh));    // lo halves
        }
        if (cnt >= KKEEP) T |= (1u << bit);
    }

    // ---- weights: w = exp(s-m) if key >= T else 0; bf16 packed write-back ----
    float ls = 0.f;
#pragma unroll 1
    for (int j = 0; j < 16; ++j) {
        unsigned lo16 = kv[j] & 0xFFFFu;
        unsigned hi16 = kv[j] >> 16;
        float wl = __expf(ord16_to_f(lo16) - m);
        float wh = __expf(ord16_to_f(hi16) - m);
        wl = (lo16 >= T) ? wl : 0.f;
        wh = (hi16 >= T) ? wh : 0.f;
        ls += wl + wh;
        rowp[lane + 64 * j] = (unsigned)f2bf(wl) | ((unsigned)f2bf(wh) << 16);
    }
#pragma unroll
    for (int off = 1; off < 64; off <<= 1) ls += __shfl_xor(ls, off, 64);
    if (lane == 0) linv[wave] = 1.f / ls;
    __syncthreads();                                       // [2] weights + linv visible

    // ---- PV: A-frags (P) from scB via b128; B-frags (V^T) from global ----
    f4 od[4];
#pragma unroll
    for (int dt = 0; dt < 4; ++dt) { f4 z = {0.f,0.f,0.f,0.f}; od[dt] = z; }
    const size_t vbb = (size_t)bh * HD_ * S_;
#pragma unroll 1
    for (int c = 0; c < 4; ++c) {
        bf8 ph = *(const bf8*)&scB[col * SRW + wave * 128 + c * 32 + quad * 8];
        const size_t sbase = (size_t)(wave * 128 + c * 32 + quad * 8);
#pragma unroll
        for (int dt = 0; dt < 4; ++dt) {
            bf8 vh = *(const bf8*)&Vthi[vbb + (size_t)(dt * 16 + col) * S_ + sbase];
            od[dt] = __builtin_amdgcn_mfma_f32_16x16x32_bf16(ph, vh, od[dt], 0, 0, 0);
        }
    }
    __syncthreads();                                       // [3] all scB reads done
#pragma unroll
    for (int dt = 0; dt < 4; ++dt)
#pragma unroll
        for (int r = 0; r < 4; ++r)
            osum[wave][quad * 4 + r][dt * 16 + col] = od[dt][r];
    __syncthreads();                                       // [4] partials visible

    // ---- final: 1024 threads cover 16x64 (q,d); sum 16 partials, emit planes ----
    {
        int q = tid >> 6, d = tid & 63;
        float s = 0.f;
#pragma unroll
        for (int w = 0; w < 16; ++w) s += osum[w][q][d];
        s *= linv[q];
        size_t idx = ((size_t)b * S_ + q0 + q) * D_ + h * HD_ + d;
        unsigned short hh = f2bf(s);
        AOhi[idx] = hh;
        AOlo[idx] = f2bf(s - bf2f(hh));
    }
}

extern "C" void kernel_launch(void* const* d_in, const int* in_sizes, int n_in,
                              void* d_out, int out_size, void* d_ws, size_t ws_size,
                              hipStream_t stream) {
    const float* x  = (const float*)d_in[0];
    const float* Wq = (const float*)d_in[1];
    const float* bq = (const float*)d_in[2];
    const float* Wk = (const float*)d_in[3];
    const float* bk = (const float*)d_in[4];
    const float* Wv = (const float*)d_in[5];
    const float* bv = (const float*)d_in[6];
    const float* Wo = (const float*)d_in[7];
    const float* bo = (const float*)d_in[8];
    float* out = (float*)d_out;

    const size_t NP = (size_t)M_ * D_;      // 3,145,728 elems
    const size_t NW = (size_t)D_ * D_;      // 589,824 elems
    unsigned short* p = (unsigned short*)d_ws;
    unsigned short* xhi = p;  p += NP;
    unsigned short* xlo = p;  p += NP;
    unsigned short* Wch = p;  p += 4 * NW;   // concatenated [Wq|Wk|Wv|Wo] hi
    unsigned short* Wcl = p;  p += 4 * NW;   // concatenated lo
    unsigned short* Qh  = p;  p += NP;  unsigned short* Ql  = p;  p += NP;
    unsigned short* Kh  = p;  p += NP;
    unsigned short* Vth = p;  p += NP;
    // AO planes alias x planes (x dead after the projections)
    unsigned short* AOh = xhi;
    unsigned short* AOl = xlo;

    split_kernel<<<(int)(NP / 256), 256, 0, stream>>>(x, xhi, xlo, (int)NP);
    {
        dim3 gw((unsigned)(NW / 256), 4);
        split_w_kernel<<<gw, 256, 0, stream>>>(Wq, Wk, Wv, Wo, Wch, Wcl);
    }

    {
        dim3 g(M_ / 128, 36);               // 3 x 768/64 column tiles
        gemm_qkv<<<g, 256, 0, stream>>>(xhi, xlo, Wch, Wcl, bq, bk, bv,
                                        Qh, Ql, Kh, Vth);
    }

    attn_kernel<<<(S_ / 16) * B_ * H_, 1024, 0, stream>>>(Qh, Ql, Kh, Vth, AOh, AOl);

    {
        dim3 g(M_ / 128, D_ / 64);
        gemm_o<<<g, 256, 0, stream>>>(AOh, AOl, Wch + 3 * NW, Wcl + 3 * NW, bo, out);
    }
}